// Round 1
// 88.799 us; speedup vs baseline: 1.0149x; 1.0149x over previous
//
#include <hip/hip_runtime.h>
#include <hip/hip_bf16.h>

#define DIM 256
#define NHEADS 8
#define HDIM 32
#define Bq 4
#define Nq 4096   // 64*64
#define Nu 1024   // 32*32

typedef __attribute__((ext_vector_type(8))) short bf16x8;
typedef __attribute__((ext_vector_type(16))) float f32x16;
typedef __attribute__((ext_vector_type(4))) unsigned short us4;

__device__ __forceinline__ ushort f2bf(float x) {
    union { float f; unsigned u; } v; v.f = x;
    unsigned r = v.u + 0x7fffu + ((v.u >> 16) & 1u);
    return (ushort)(r >> 16);
}
__device__ __forceinline__ float bf2f(ushort u) {
    union { unsigned u; float f; } v; v.u = ((unsigned)u) << 16;
    return v.f;
}

// ---------------------------------------------------------------------------
// prepro (merged): blocks [0,512): weight casts; [512,1536): transpose x;
// [1536,1792): transpose upper.  Transpose: In [b][C][N] f32 -> OutT [b][N][C] bf16.
// ---------------------------------------------------------------------------
__global__ __launch_bounds__(256) void prepro(
    const float* __restrict__ Wq, ushort* __restrict__ Oq,
    const float* __restrict__ Wkv, ushort* __restrict__ Okv,
    const float* __restrict__ Wp, ushort* __restrict__ Oph, ushort* __restrict__ Opl,
    const float* __restrict__ x, ushort* __restrict__ xT,
    const float* __restrict__ upper, ushort* __restrict__ upT)
{
    __shared__ ushort T[64][66];
    const int id = blockIdx.x;
    const int tid = threadIdx.x;

    if (id < 512) {
        int i = id * 256 + tid;
        if (i < 65536) {
            Oq[i] = f2bf(Wq[i]);
            float w = Wp[i];
            ushort h = f2bf(w);
            Oph[i] = h;
            Opl[i] = f2bf(w - bf2f(h));
        }
        Okv[i] = f2bf(Wkv[i]);
        return;
    }

    const float* In; ushort* OutT; int N, n0, c0, b;
    if (id < 1536) {
        int q = id - 512;               // x: grid (64,4,4)
        In = x; OutT = xT; N = 4096;
        n0 = (q & 63) * 64; c0 = ((q >> 6) & 3) * 64; b = q >> 8;
    } else {
        int q = id - 1536;              // upper: grid (16,4,4)
        In = upper; OutT = upT; N = 1024;
        n0 = (q & 15) * 64; c0 = ((q >> 4) & 3) * 64; b = q >> 6;
    }

    const float* Ib = In + ((size_t)b * 256 + c0) * N + n0;
    const int nx = (tid & 15) * 4, cy = tid >> 4;
    #pragma unroll
    for (int p = 0; p < 4; ++p) {
        float4 v = *(const float4*)(Ib + (size_t)(cy + p * 16) * N + nx);
        T[nx + 0][cy + p * 16] = f2bf(v.x);
        T[nx + 1][cy + p * 16] = f2bf(v.y);
        T[nx + 2][cy + p * 16] = f2bf(v.z);
        T[nx + 3][cy + p * 16] = f2bf(v.w);
    }
    __syncthreads();
    ushort* Ob = OutT + ((size_t)b * N + n0) * 256 + c0;
    #pragma unroll
    for (int p = 0; p < 4; ++p) {
        int row = (tid >> 4) + p * 16;
        *(us4*)(Ob + (size_t)row * 256 + (tid & 15) * 4) = *(const us4*)&T[row][(tid & 15) * 4];
    }
}

// ---------------------------------------------------------------------------
// qkv (merged): blocks [0,512): Q projection (MODE1); [512,768): KV (MODE2).
// Zero-LDS bf16 MFMA GEMM, K=256, wave = 32o x 64n.
// ---------------------------------------------------------------------------
__global__ __launch_bounds__(256, 4) void qkv_mfma(
    const ushort* __restrict__ Wqb, const ushort* __restrict__ xT,
    const float* __restrict__ q_scale, const float* __restrict__ q_bias, float qmult,
    const ushort* __restrict__ Wkvb, const ushort* __restrict__ upT,
    const float* __restrict__ kv_scale, const float* __restrict__ kv_bias,
    ushort* __restrict__ Qb, ushort* __restrict__ Kb, ushort* __restrict__ Vb)
{
    const int KD = 256;
    const int id = blockIdx.x;
    const int tid = threadIdx.x;
    const int w = tid >> 6, l = tid & 63;
    const int l31 = l & 31, hi = l >> 5;

    const ushort *Wb, *InT, *OutA; const float *scale, *bias;
    int N, n0, o0, b; float mult; bool isT; int bh;
    if (id < 512) {                        // Q: grid (16,8,4)
        int q = id;
        int bx = q & 15, by = (q >> 4) & 7; b = q >> 7;
        N = 4096; n0 = (bx * 4 + w) * 64; o0 = by * 32;
        Wb = Wqb; InT = xT; scale = q_scale; bias = q_bias; mult = qmult;
        isT = true; bh = b * 8 + (o0 >> 5);
        OutA = Qb;
    } else {                               // KV: grid (4,16,4)
        int q = id - 512;
        int bx = q & 3, by = (q >> 2) & 15; b = q >> 6;
        N = 1024; n0 = (bx * 4 + w) * 64; o0 = by * 32;
        Wb = Wkvb; InT = upT; scale = kv_scale; bias = kv_bias; mult = 1.0f;
        isT = ((o0 & 32) == 0); bh = b * 8 + (o0 >> 6);
        OutA = Kb;
    }

    const ushort* Wp = Wb + (size_t)(o0 + l31) * KD + hi * 8;
    const ushort* I0 = InT + ((size_t)b * N + n0 + l31) * KD + hi * 8;
    const ushort* I1 = I0 + (size_t)32 * KD;

    f32x16 acc0 = {}, acc1 = {};
    if (isT) {
        #pragma unroll 8
        for (int kk = 0; kk < KD; kk += 16) {
            bf16x8 wv = *(const bf16x8*)(Wp + kk);
            bf16x8 i0 = *(const bf16x8*)(I0 + kk);
            bf16x8 i1 = *(const bf16x8*)(I1 + kk);
            acc0 = __builtin_amdgcn_mfma_f32_32x32x16_bf16(i0, wv, acc0, 0, 0, 0);
            acc1 = __builtin_amdgcn_mfma_f32_32x32x16_bf16(i1, wv, acc1, 0, 0, 0);
        }
        const float sc = scale[o0 + l31] * mult;
        const float bi = bias[o0 + l31] * mult;
        ushort* Oa = (ushort*)OutA + ((size_t)bh * N) * 32 + l31;
        #pragma unroll
        for (int r = 0; r < 16; ++r) {
            const int dn = (r & 3) + 8 * (r >> 2) + 4 * hi;
            Oa[(size_t)(n0 + dn) * 32]      = f2bf(acc0[r] * sc + bi);
            Oa[(size_t)(n0 + 32 + dn) * 32] = f2bf(acc1[r] * sc + bi);
        }
    } else {
        #pragma unroll 8
        for (int kk = 0; kk < KD; kk += 16) {
            bf16x8 wv = *(const bf16x8*)(Wp + kk);
            bf16x8 i0 = *(const bf16x8*)(I0 + kk);
            bf16x8 i1 = *(const bf16x8*)(I1 + kk);
            acc0 = __builtin_amdgcn_mfma_f32_32x32x16_bf16(wv, i0, acc0, 0, 0, 0);
            acc1 = __builtin_amdgcn_mfma_f32_32x32x16_bf16(wv, i1, acc1, 0, 0, 0);
        }
        ushort* Ob = Vb + (size_t)bh * 32 * N;
        #pragma unroll
        for (int r = 0; r < 16; ++r) {
            const int dr = (r & 3) + 8 * (r >> 2) + 4 * hi;
            const float sc = scale[o0 + dr], bi = bias[o0 + dr];
            Ob[(size_t)dr * N + n0 + l31]      = f2bf(acc0[r] * sc + bi);
            Ob[(size_t)dr * N + n0 + 32 + l31] = f2bf(acc1[r] * sc + bi);
        }
    }
}

// ---------------------------------------------------------------------------
// attn_dw (merged): blocks [0,1024): flash attention (round-8 structure,
// bf16 output); [1024,2048): depthwise 7x7 + upsample (bf16 output).
// Shared 16KB LDS union.
// ---------------------------------------------------------------------------
__global__ __launch_bounds__(256, 4) void attn_dw(
    const ushort* __restrict__ Qb, const ushort* __restrict__ Kt,
    const ushort* __restrict__ Vb, ushort* __restrict__ ao,
    const float* __restrict__ Wpe, const float* __restrict__ pe_scale,
    const float* __restrict__ pe_bias, ushort* __restrict__ vpe)
{
    __shared__ __align__(16) unsigned char smem[16384];
    const int tid = threadIdx.x;

    if (blockIdx.x < 1024) {
        // ---- attention ----
        const int w = tid >> 6, l = tid & 63;
        const int l31 = l & 31, hi = l >> 5;
        const int lid = blockIdx.x;
        const int j = lid >> 3;
        const int bh = (lid & 7) * 4 + (j >> 5);
        const int qbase = (j & 31) * 128 + w * 32;

        unsigned char (*ldsbuf)[8192] = (unsigned char(*)[8192])smem;

        const ushort* Qp = Qb + ((size_t)bh * 4096 + qbase) * 32;
        const unsigned char* Kg = (const unsigned char*)(Kt + (size_t)bh * 1024 * 32);
        const unsigned char* Vg = (const unsigned char*)(Vb + (size_t)bh * 32 * 1024);

        const bf16x8 qb0 = *(const bf16x8*)(Qp + (size_t)l31 * 32 + hi * 8);
        const bf16x8 qb1 = *(const bf16x8*)(Qp + (size_t)l31 * 32 + 16 + hi * 8);

        const int kr = tid >> 2, kc = tid & 3;
        const int vd = tid >> 3, vc = tid & 7;
        const int kwr = (kr * 64 + kc * 16) ^ ((kr & 7) << 4);
        const int vwr = vd * 128 + ((vc ^ (vd & 7)) << 4);

        f32x16 acc = {};
        float l_run = 0.f;

        uint4 kreg = *(const uint4*)(Kg + kr * 64 + kc * 16);
        uint4 vreg = *(const uint4*)(Vg + vd * 2048 + vc * 16);
        *(uint4*)(&ldsbuf[0][kwr]) = kreg;
        *(uint4*)(&ldsbuf[0][4096 + vwr]) = vreg;
        __syncthreads();

        for (int ph = 0; ph < 16; ++ph) {
            const int cur = ph & 1;
            if (ph < 15) {
                const size_t koff = (size_t)(ph + 1) * 4096;
                const int    voff = (ph + 1) * 128;
                kreg = *(const uint4*)(Kg + koff + kr * 64 + kc * 16);
                vreg = *(const uint4*)(Vg + (size_t)vd * 2048 + voff + vc * 16);
            }
            const unsigned char* Kl = &ldsbuf[cur][0];
            const unsigned char* Vl = &ldsbuf[cur][4096];

            #pragma unroll
            for (int s = 0; s < 2; ++s) {
                const int r = s * 32 + l31;
                bf16x8 ka0 = *(const bf16x8*)(Kl + ((r * 64 + hi * 16) ^ ((r & 7) << 4)));
                bf16x8 ka1 = *(const bf16x8*)(Kl + ((r * 64 + 32 + hi * 16) ^ ((r & 7) << 4)));
                bf16x8 va0 = *(const bf16x8*)(Vl + l31 * 128 + (((s * 4 + hi)     ^ (l31 & 7)) << 4));
                bf16x8 va1 = *(const bf16x8*)(Vl + l31 * 128 + (((s * 4 + 2 + hi) ^ (l31 & 7)) << 4));

                f32x16 sv = {};
                sv = __builtin_amdgcn_mfma_f32_32x32x16_bf16(ka0, qb0, sv, 0, 0, 0);
                sv = __builtin_amdgcn_mfma_f32_32x32x16_bf16(ka1, qb1, sv, 0, 0, 0);

                float p[16];
                #pragma unroll
                for (int r2 = 0; r2 < 16; ++r2) p[r2] = __builtin_amdgcn_exp2f(sv[r2]);
                l_run += (((p[0] + p[1]) + (p[2] + p[3])) + ((p[4] + p[5]) + (p[6] + p[7])))
                       + (((p[8] + p[9]) + (p[10] + p[11])) + ((p[12] + p[13]) + (p[14] + p[15])));

                int c[8];
                #pragma unroll
                for (int i = 0; i < 8; ++i)
                    asm("v_cvt_pk_bf16_f32 %0, %1, %2" : "=v"(c[i]) : "v"(p[2 * i]), "v"(p[2 * i + 1]));
                asm("v_permlane32_swap_b32 %0, %1" : "+v"(c[0]), "+v"(c[2]));
                asm("v_permlane32_swap_b32 %0, %1" : "+v"(c[1]), "+v"(c[3]));
                asm("v_permlane32_swap_b32 %0, %1" : "+v"(c[4]), "+v"(c[6]));
                asm("v_permlane32_swap_b32 %0, %1" : "+v"(c[5]), "+v"(c[7]));

                union { int i[4]; bf16x8 v; } b0u, b1u;
                b0u.i[0] = c[0]; b0u.i[1] = c[1]; b0u.i[2] = c[2]; b0u.i[3] = c[3];
                b1u.i[0] = c[4]; b1u.i[1] = c[5]; b1u.i[2] = c[6]; b1u.i[3] = c[7];

                acc = __builtin_amdgcn_mfma_f32_32x32x16_bf16(va0, b0u.v, acc, 0, 0, 0);
                acc = __builtin_amdgcn_mfma_f32_32x32x16_bf16(va1, b1u.v, acc, 0, 0, 0);
            }

            if (ph < 15) {
                const int nxt = cur ^ 1;
                *(uint4*)(&ldsbuf[nxt][kwr]) = kreg;
                *(uint4*)(&ldsbuf[nxt][4096 + vwr]) = vreg;
            }
            __syncthreads();
        }

        l_run += __shfl_xor(l_run, 32);
        float inv = 1.0f / l_run;

        ushort* aob = ao + ((size_t)(bh >> 3) * 256 + (bh & 7) * 32) * 4096 + qbase + l31;
        #pragma unroll
        for (int r = 0; r < 16; ++r) {
            const int d = (r & 3) + 8 * (r >> 2) + 4 * hi;
            aob[(size_t)d * 4096] = f2bf(acc[r] * inv);
        }
    } else {
        // ---- depthwise 7x7 + bilinear upsample ----
        const int bc = blockIdx.x - 1024;
        const int b = bc >> 8, c = bc & 255;
        const ushort* vp = Vb + ((size_t)(b * 8 + (c >> 5)) * 32 + (c & 31)) * 1024;

        float* t   = (float*)smem;              // 38*38*4 = 5776 B
        float* v32 = (float*)(smem + 5776);     // 4096 B
        float* wl  = (float*)(smem + 9872);     // 196 B

        for (int i = tid; i < 38 * 38; i += 256) {
            int yy = i / 38 - 3, xx = i % 38 - 3;
            t[i] = (yy >= 0 && yy < 32 && xx >= 0 && xx < 32) ? bf2f(vp[yy * 32 + xx]) : 0.f;
        }
        if (tid < 49) wl[tid] = Wpe[(size_t)c * 49 + tid];
        __syncthreads();

        const float sc = pe_scale[c], bi = pe_bias[c];
        for (int i = tid; i < 1024; i += 256) {
            int y = i >> 5, x = i & 31;
            float s = 0.f;
            #pragma unroll
            for (int ky = 0; ky < 7; ++ky)
                #pragma unroll
                for (int kx = 0; kx < 7; ++kx)
                    s += t[(y + ky) * 38 + x + kx] * wl[ky * 7 + kx];
            v32[i] = s * sc + bi;
        }
        __syncthreads();

        ushort* op = vpe + (size_t)bc * 4096;
        #pragma unroll
        for (int p = 0; p < 16; ++p) {
            int idx = p * 256 + tid;
            int x = idx & 63, y = idx >> 6;
            float cx = x * 0.5f - 0.25f;
            float cy = y * 0.5f - 0.25f;
            int x0 = (x - 1) >> 1, y0 = (y - 1) >> 1;
            float fx = cx - x0, fy = cy - y0;
            int x0c = max(x0, 0), x1c = min(x0 + 1, 31);
            int y0c = max(y0, 0), y1c = min(y0 + 1, 31);
            float v00 = v32[y0c * 32 + x0c], v01 = v32[y0c * 32 + x1c];
            float v10 = v32[y1c * 32 + x0c], v11 = v32[y1c * 32 + x1c];
            float val = (1.f - fy) * ((1.f - fx) * v00 + fx * v01)
                      + fy * ((1.f - fx) * v10 + fx * v11);
            op[idx] = f2bf(val);
        }
    }
}

// ---------------------------------------------------------------------------
// Output projection, fused with the transpose+add that used to be `prep`:
// stages S[n][c] = (ao + vpe)^T through LDS (XOR-swizzled), then
// C = Whi*S + Wlo*S.  Block: o=128 x n=64; wave: o=64 (2 acc tiles) x n=32,
// so one A-fragment ds_read_b128 feeds 4 MFMAs (LDS not oversubscribed).
// ---------------------------------------------------------------------------
__global__ __launch_bounds__(256, 2) void proj_mfma(
    const ushort* __restrict__ Whi, const ushort* __restrict__ Wlo,
    const ushort* __restrict__ ao, const ushort* __restrict__ vpe,
    const float* __restrict__ scale, const float* __restrict__ bias,
    float* __restrict__ Out)
{
    __shared__ __align__(16) ushort S[64 * 256];   // 32 KB, swizzled [n][c]
    const int tid = threadIdx.x;
    const int b  = blockIdx.z;
    const int n0 = blockIdx.x * 64;        // 64 n-blocks
    const int o0 = blockIdx.y * 128;       // 2 o-blocks

    // ---- stage S[n][c] = ao[c][n] + vpe[c][n] (exact bf16 add as in prep) ----
    {
        const int n8 = (tid & 7) * 8;          // local n base (8 rows)
        const int c8 = (tid >> 3) * 8;         // c base (8 rows of source)
        const ushort* ap = ao  + ((size_t)b * 256 + c8) * 4096 + n0 + n8;
        const ushort* vp = vpe + ((size_t)b * 256 + c8) * 4096 + n0 + n8;
        unsigned ow[8][4];                     // [local n j][c-pair rp]
        #pragma unroll
        for (int rp = 0; rp < 4; ++rp) {
            uint4 a0 = *(const uint4*)(ap + (size_t)(2 * rp) * 4096);
            uint4 a1 = *(const uint4*)(ap + (size_t)(2 * rp + 1) * 4096);
            uint4 v0 = *(const uint4*)(vp + (size_t)(2 * rp) * 4096);
            uint4 v1 = *(const uint4*)(vp + (size_t)(2 * rp + 1) * 4096);
            const unsigned* a0u = (const unsigned*)&a0;
            const unsigned* a1u = (const unsigned*)&a1;
            const unsigned* v0u = (const unsigned*)&v0;
            const unsigned* v1u = (const unsigned*)&v1;
            #pragma unroll
            for (int q = 0; q < 4; ++q) {
                // unpack 2 bf16 per u32 into f32 halves (exact), add in f32
                float s0lo = __uint_as_float(a0u[q] << 16)
                           + __uint_as_float(v0u[q] << 16);
                float s0hi = __uint_as_float(a0u[q] & 0xffff0000u)
                           + __uint_as_float(v0u[q] & 0xffff0000u);
                float s1lo = __uint_as_float(a1u[q] << 16)
                           + __uint_as_float(v1u[q] << 16);
                float s1hi = __uint_as_float(a1u[q] & 0xffff0000u)
                           + __uint_as_float(v1u[q] & 0xffff0000u);
                unsigned plo, phi;
                // pack along c: (c=2rp, c=2rp+1) for n = n8+2q / n8+2q+1
                asm("v_cvt_pk_bf16_f32 %0, %1, %2" : "=v"(plo) : "v"(s0lo), "v"(s1lo));
                asm("v_cvt_pk_bf16_f32 %0, %1, %2" : "=v"(phi) : "v"(s0hi), "v"(s1hi));
                ow[2 * q][rp]     = plo;
                ow[2 * q + 1][rp] = phi;
            }
        }
        #pragma unroll
        for (int j = 0; j < 8; ++j) {
            const int n = n8 + j;
            const int slot = (((c8 >> 3) ^ (n & 15)) & 31);
            *(uint4*)(&S[n * 256 + (slot << 3)]) = *(const uint4*)&ow[j][0];
        }
    }
    __syncthreads();

    // ---- GEMM ----
    const int w = tid >> 6, l = tid & 63;
    const int l31 = l & 31, hi = l >> 5;
    const int wo = w >> 1, wn = w & 1;     // wave: o-half (64), n-half (32)
    const int ob = o0 + wo * 64;

    const ushort* wh0 = Whi + (size_t)(ob + l31) * 256 + hi * 8;
    const ushort* wh1 = wh0 + (size_t)32 * 256;
    const ushort* wl0 = Wlo + (size_t)(ob + l31) * 256 + hi * 8;
    const ushort* wl1 = wl0 + (size_t)32 * 256;

    const int nloc = wn * 32 + l31;
    const ushort* Srow = &S[nloc * 256];
    const int nsw = nloc & 15;

    f32x16 acc0 = {}, acc1 = {};           // acc0: o in [ob,ob+32), acc1: +32
    #pragma unroll 4
    for (int kk = 0; kk < 256; kk += 16) {
        const int slot = (((kk >> 3) + hi) ^ nsw) & 31;
        bf16x8 av = *(const bf16x8*)(Srow + (slot << 3));
        bf16x8 h0 = *(const bf16x8*)(wh0 + kk);
        bf16x8 h1 = *(const bf16x8*)(wh1 + kk);
        bf16x8 g0 = *(const bf16x8*)(wl0 + kk);
        bf16x8 g1 = *(const bf16x8*)(wl1 + kk);
        acc0 = __builtin_amdgcn_mfma_f32_32x32x16_bf16(h0, av, acc0, 0, 0, 0);
        acc1 = __builtin_amdgcn_mfma_f32_32x32x16_bf16(h1, av, acc1, 0, 0, 0);
        acc0 = __builtin_amdgcn_mfma_f32_32x32x16_bf16(g0, av, acc0, 0, 0, 0);
        acc1 = __builtin_amdgcn_mfma_f32_32x32x16_bf16(g1, av, acc1, 0, 0, 0);
    }

    float* Ob = Out + (size_t)b * 256 * 4096 + n0 + wn * 32 + l31;
    #pragma unroll
    for (int r = 0; r < 16; ++r) {
        const int dr = (r & 3) + 8 * (r >> 2) + 4 * hi;
        const int oA = ob + dr, oB = ob + 32 + dr;
        Ob[(size_t)oA * 4096] = acc0[r] * scale[oA] + bias[oA];
        Ob[(size_t)oB * 4096] = acc1[r] * scale[oB] + bias[oB];
    }
}

// ---------------------------------------------------------------------------
extern "C" void kernel_launch(void* const* d_in, const int* in_sizes, int n_in,
                              void* d_out, int out_size, void* d_ws, size_t ws_size,
                              hipStream_t stream)
{
    const float* x        = (const float*)d_in[0];
    const float* upper    = (const float*)d_in[1];
    const float* Wq       = (const float*)d_in[2];
    const float* q_scale  = (const float*)d_in[3];
    const float* q_bias   = (const float*)d_in[4];
    const float* Wkv      = (const float*)d_in[5];
    const float* kv_scale = (const float*)d_in[6];
    const float* kv_bias  = (const float*)d_in[7];
    const float* Wpe      = (const float*)d_in[8];
    const float* pe_scale = (const float*)d_in[9];
    const float* pe_bias  = (const float*)d_in[10];
    const float* Wproj    = (const float*)d_in[11];
    const float* proj_scale = (const float*)d_in[12];
    const float* proj_bias  = (const float*)d_in[13];
    float* out = (float*)d_out;

    ushort* Qb   = (ushort*)d_ws;                           // 8.39 MB
    ushort* Kb   = Qb + (size_t)32 * 4096 * 32;             // 2.10 MB
    ushort* Vb   = Kb + (size_t)32 * 1024 * 32;             // 2.10 MB
    ushort* ao   = Vb + (size_t)32 * 1024 * 32;             // 8.39 MB bf16 [b][256][4096]
    ushort* vpe  = ao + (size_t)Bq * DIM * Nq;              // 8.39 MB bf16 [b][256][4096] (old AT space)
    ushort* Wqb  = vpe + (size_t)Bq * DIM * Nq;             // 128 KB
    ushort* Wkvb = Wqb + 256 * 256;                         // 256 KB
    ushort* Wph  = Wkvb + 512 * 256;                        // 128 KB
    ushort* Wpl  = Wph + 256 * 256;                         // 128 KB
    // aliases:
    ushort* xT   = ao;                                      // consumed by qkv before attn writes ao
    ushort* upT  = vpe;                                     // consumed by qkv before dw writes vpe

    const float qmult = 0.17677669529663687f * 1.4426950408889634f; // qscale*log2e

    prepro<<<dim3(1792), 256, 0, stream>>>(Wq, Wqb, Wkv, Wkvb, Wproj, Wph, Wpl,
                                           x, xT, upper, upT);

    qkv_mfma<<<dim3(768), 256, 0, stream>>>(Wqb, xT, q_scale, q_bias, qmult,
                                            Wkvb, upT, kv_scale, kv_bias,
                                            Qb, Kb, Vb);

    attn_dw<<<dim3(2048), 256, 0, stream>>>(Qb, Kb, Vb, ao,
                                            Wpe, pe_scale, pe_bias, vpe);

    proj_mfma<<<dim3(64, 2, 4), 256, 0, stream>>>(Wph, Wpl, ao, vpe,
                                                  proj_scale, proj_bias, out);
}

// Round 2
// 82.473 us; speedup vs baseline: 1.0928x; 1.0767x over previous
//
#include <hip/hip_runtime.h>
#include <hip/hip_bf16.h>

#define DIM 256
#define NHEADS 8
#define HDIM 32
#define Bq 4
#define Nq 4096   // 64*64
#define Nu 1024   // 32*32

typedef __attribute__((ext_vector_type(8))) short bf16x8;
typedef __attribute__((ext_vector_type(16))) float f32x16;
typedef __attribute__((ext_vector_type(4))) unsigned short us4;

__device__ __forceinline__ ushort f2bf(float x) {
    union { float f; unsigned u; } v; v.f = x;
    unsigned r = v.u + 0x7fffu + ((v.u >> 16) & 1u);
    return (ushort)(r >> 16);
}
__device__ __forceinline__ float bf2f(ushort u) {
    union { unsigned u; float f; } v; v.u = ((unsigned)u) << 16;
    return v.f;
}

// ---------------------------------------------------------------------------
// prepro: weight casts only (x/upper transposes are now fused into qkv).
// grid 512 x 256 threads.
// ---------------------------------------------------------------------------
__global__ __launch_bounds__(256) void prepro(
    const float* __restrict__ Wq, ushort* __restrict__ Oq,
    const float* __restrict__ Wkv, ushort* __restrict__ Okv,
    const float* __restrict__ Wp, ushort* __restrict__ Oph, ushort* __restrict__ Opl)
{
    const int i = blockIdx.x * 256 + threadIdx.x;
    if (i < 65536) {
        Oq[i] = f2bf(Wq[i]);
        float w = Wp[i];
        ushort h = f2bf(w);
        Oph[i] = h;
        Opl[i] = f2bf(w - bf2f(h));
    }
    Okv[i] = f2bf(Wkv[i]);
}

// ---------------------------------------------------------------------------
// qkv (fused transpose + GEMM): blocks [0,512): Q (128 n-blocks x 4 b);
// [512,768): KV (32 n-blocks x 2 o-halves x 4 b).
// Stages a [32 n][256 c] bf16 tile of fp32 input through swizzled LDS
// (in-register cvt_pk transpose), then each wave computes 64 output rows:
// Q: heads 2w,2w+1; KV: head oh*4+w's K (transposed out) + V (direct out).
// ---------------------------------------------------------------------------
__global__ __launch_bounds__(256, 4) void qkv_mfma(
    const ushort* __restrict__ Wqb, const float* __restrict__ x,
    const float* __restrict__ q_scale, const float* __restrict__ q_bias, float qmult,
    const ushort* __restrict__ Wkvb, const float* __restrict__ upper,
    const float* __restrict__ kv_scale, const float* __restrict__ kv_bias,
    ushort* __restrict__ Qb, ushort* __restrict__ Kb, ushort* __restrict__ Vb)
{
    __shared__ __align__(16) ushort S[32 * 256];   // 16 KB, swizzled [n][c]
    const int id = blockIdx.x;
    const int tid = threadIdx.x;

    const float* In; int N, n0, b, oh; bool isQ;
    if (id < 512) {
        isQ = true; In = x; N = 4096;
        n0 = (id & 127) * 32; b = id >> 7; oh = 0;
    } else {
        int q = id - 512;
        isQ = false; In = upper; N = 1024;
        n0 = (q & 31) * 32; oh = (q >> 5) & 1; b = q >> 6;
    }

    // ---- stage S[n][c] = bf16(In[c][n]) ----
    {
        const int n4 = (tid & 7) * 4, c8 = (tid >> 3) * 8;
        const float* ip = In + ((size_t)b * 256 + c8) * N + n0 + n4;
        unsigned ow[4][4];                 // [local n j][c-pair rp]
        #pragma unroll
        for (int rp = 0; rp < 4; ++rp) {
            float4 f0 = *(const float4*)(ip + (size_t)(2 * rp) * N);
            float4 f1 = *(const float4*)(ip + (size_t)(2 * rp + 1) * N);
            asm("v_cvt_pk_bf16_f32 %0, %1, %2" : "=v"(ow[0][rp]) : "v"(f0.x), "v"(f1.x));
            asm("v_cvt_pk_bf16_f32 %0, %1, %2" : "=v"(ow[1][rp]) : "v"(f0.y), "v"(f1.y));
            asm("v_cvt_pk_bf16_f32 %0, %1, %2" : "=v"(ow[2][rp]) : "v"(f0.z), "v"(f1.z));
            asm("v_cvt_pk_bf16_f32 %0, %1, %2" : "=v"(ow[3][rp]) : "v"(f0.w), "v"(f1.w));
        }
        #pragma unroll
        for (int j = 0; j < 4; ++j) {
            const int n = n4 + j;
            const int slot = ((c8 >> 3) ^ (n & 15)) & 31;
            *(uint4*)(&S[n * 256 + (slot << 3)]) = *(const uint4*)&ow[j][0];
        }
    }
    __syncthreads();

    const int w = tid >> 6, l = tid & 63;
    const int l31 = l & 31, hi = l >> 5;
    const int nsw = l31 & 15;
    const ushort* Srow = &S[l31 * 256];

    if (isQ) {
        const ushort* w0 = Wqb + (size_t)(w * 64 + l31) * 256 + hi * 8;
        const ushort* w1 = w0 + (size_t)32 * 256;
        f32x16 acc0 = {}, acc1 = {};
        #pragma unroll 8
        for (int kk = 0; kk < 256; kk += 16) {
            const int slot = (((kk >> 3) + hi) ^ nsw) & 31;
            bf16x8 av = *(const bf16x8*)(Srow + (slot << 3));
            bf16x8 h0 = *(const bf16x8*)(w0 + kk);
            bf16x8 h1 = *(const bf16x8*)(w1 + kk);
            acc0 = __builtin_amdgcn_mfma_f32_32x32x16_bf16(av, h0, acc0, 0, 0, 0);
            acc1 = __builtin_amdgcn_mfma_f32_32x32x16_bf16(av, h1, acc1, 0, 0, 0);
        }
        #pragma unroll
        for (int t = 0; t < 2; ++t) {
            const f32x16 a = t ? acc1 : acc0;
            const int orow = w * 64 + t * 32 + l31;
            const float sc = q_scale[orow] * qmult;
            const float bi = q_bias[orow] * qmult;
            const int bh = b * 8 + 2 * w + t;
            ushort* Oa = Qb + ((size_t)bh * 4096) * 32 + l31;
            #pragma unroll
            for (int r = 0; r < 16; ++r) {
                const int dn = (r & 3) + 8 * (r >> 2) + 4 * hi;
                Oa[(size_t)(n0 + dn) * 32] = f2bf(a[r] * sc + bi);
            }
        }
    } else {
        const int h = oh * 4 + w;
        const ushort* wk = Wkvb + (size_t)(h * 64 + l31) * 256 + hi * 8;
        const ushort* wv = wk + (size_t)32 * 256;
        f32x16 accK = {}, accV = {};
        #pragma unroll 8
        for (int kk = 0; kk < 256; kk += 16) {
            const int slot = (((kk >> 3) + hi) ^ nsw) & 31;
            bf16x8 av = *(const bf16x8*)(Srow + (slot << 3));
            bf16x8 k0 = *(const bf16x8*)(wk + kk);
            bf16x8 v0 = *(const bf16x8*)(wv + kk);
            accK = __builtin_amdgcn_mfma_f32_32x32x16_bf16(av, k0, accK, 0, 0, 0);
            accV = __builtin_amdgcn_mfma_f32_32x32x16_bf16(v0, av, accV, 0, 0, 0);
        }
        const int bh = b * 8 + h;
        {
            const float sc = kv_scale[h * 64 + l31];
            const float bi = kv_bias[h * 64 + l31];
            ushort* Oa = Kb + ((size_t)bh * 1024) * 32 + l31;
            #pragma unroll
            for (int r = 0; r < 16; ++r) {
                const int dn = (r & 3) + 8 * (r >> 2) + 4 * hi;
                Oa[(size_t)(n0 + dn) * 32] = f2bf(accK[r] * sc + bi);
            }
        }
        {
            ushort* Ob = Vb + (size_t)bh * 32 * 1024;
            #pragma unroll
            for (int r = 0; r < 16; ++r) {
                const int dr = (r & 3) + 8 * (r >> 2) + 4 * hi;
                const float sc = kv_scale[h * 64 + 32 + dr];
                const float bi = kv_bias[h * 64 + 32 + dr];
                Ob[(size_t)dr * 1024 + n0 + l31] = f2bf(accV[r] * sc + bi);
            }
        }
    }
}

// ---------------------------------------------------------------------------
// attn_dw (merged): blocks [0,1024): flash attention (round-8 structure,
// bf16 output); [1024,2048): depthwise 7x7 + upsample (bf16 output).
// Shared 16KB LDS union.
// ---------------------------------------------------------------------------
__global__ __launch_bounds__(256, 4) void attn_dw(
    const ushort* __restrict__ Qb, const ushort* __restrict__ Kt,
    const ushort* __restrict__ Vb, ushort* __restrict__ ao,
    const float* __restrict__ Wpe, const float* __restrict__ pe_scale,
    const float* __restrict__ pe_bias, ushort* __restrict__ vpe)
{
    __shared__ __align__(16) unsigned char smem[16384];
    const int tid = threadIdx.x;

    if (blockIdx.x < 1024) {
        // ---- attention ----
        const int w = tid >> 6, l = tid & 63;
        const int l31 = l & 31, hi = l >> 5;
        const int lid = blockIdx.x;
        const int j = lid >> 3;
        const int bh = (lid & 7) * 4 + (j >> 5);
        const int qbase = (j & 31) * 128 + w * 32;

        unsigned char (*ldsbuf)[8192] = (unsigned char(*)[8192])smem;

        const ushort* Qp = Qb + ((size_t)bh * 4096 + qbase) * 32;
        const unsigned char* Kg = (const unsigned char*)(Kt + (size_t)bh * 1024 * 32);
        const unsigned char* Vg = (const unsigned char*)(Vb + (size_t)bh * 32 * 1024);

        const bf16x8 qb0 = *(const bf16x8*)(Qp + (size_t)l31 * 32 + hi * 8);
        const bf16x8 qb1 = *(const bf16x8*)(Qp + (size_t)l31 * 32 + 16 + hi * 8);

        const int kr = tid >> 2, kc = tid & 3;
        const int vd = tid >> 3, vc = tid & 7;
        const int kwr = (kr * 64 + kc * 16) ^ ((kr & 7) << 4);
        const int vwr = vd * 128 + ((vc ^ (vd & 7)) << 4);

        f32x16 acc = {};
        float l_run = 0.f;

        uint4 kreg = *(const uint4*)(Kg + kr * 64 + kc * 16);
        uint4 vreg = *(const uint4*)(Vg + vd * 2048 + vc * 16);
        *(uint4*)(&ldsbuf[0][kwr]) = kreg;
        *(uint4*)(&ldsbuf[0][4096 + vwr]) = vreg;
        __syncthreads();

        for (int ph = 0; ph < 16; ++ph) {
            const int cur = ph & 1;
            if (ph < 15) {
                const size_t koff = (size_t)(ph + 1) * 4096;
                const int    voff = (ph + 1) * 128;
                kreg = *(const uint4*)(Kg + koff + kr * 64 + kc * 16);
                vreg = *(const uint4*)(Vg + (size_t)vd * 2048 + voff + vc * 16);
            }
            const unsigned char* Kl = &ldsbuf[cur][0];
            const unsigned char* Vl = &ldsbuf[cur][4096];

            #pragma unroll
            for (int s = 0; s < 2; ++s) {
                const int r = s * 32 + l31;
                bf16x8 ka0 = *(const bf16x8*)(Kl + ((r * 64 + hi * 16) ^ ((r & 7) << 4)));
                bf16x8 ka1 = *(const bf16x8*)(Kl + ((r * 64 + 32 + hi * 16) ^ ((r & 7) << 4)));
                bf16x8 va0 = *(const bf16x8*)(Vl + l31 * 128 + (((s * 4 + hi)     ^ (l31 & 7)) << 4));
                bf16x8 va1 = *(const bf16x8*)(Vl + l31 * 128 + (((s * 4 + 2 + hi) ^ (l31 & 7)) << 4));

                f32x16 sv = {};
                sv = __builtin_amdgcn_mfma_f32_32x32x16_bf16(ka0, qb0, sv, 0, 0, 0);
                sv = __builtin_amdgcn_mfma_f32_32x32x16_bf16(ka1, qb1, sv, 0, 0, 0);

                float p[16];
                #pragma unroll
                for (int r2 = 0; r2 < 16; ++r2) p[r2] = __builtin_amdgcn_exp2f(sv[r2]);
                l_run += (((p[0] + p[1]) + (p[2] + p[3])) + ((p[4] + p[5]) + (p[6] + p[7])))
                       + (((p[8] + p[9]) + (p[10] + p[11])) + ((p[12] + p[13]) + (p[14] + p[15])));

                int c[8];
                #pragma unroll
                for (int i = 0; i < 8; ++i)
                    asm("v_cvt_pk_bf16_f32 %0, %1, %2" : "=v"(c[i]) : "v"(p[2 * i]), "v"(p[2 * i + 1]));
                asm("v_permlane32_swap_b32 %0, %1" : "+v"(c[0]), "+v"(c[2]));
                asm("v_permlane32_swap_b32 %0, %1" : "+v"(c[1]), "+v"(c[3]));
                asm("v_permlane32_swap_b32 %0, %1" : "+v"(c[4]), "+v"(c[6]));
                asm("v_permlane32_swap_b32 %0, %1" : "+v"(c[5]), "+v"(c[7]));

                union { int i[4]; bf16x8 v; } b0u, b1u;
                b0u.i[0] = c[0]; b0u.i[1] = c[1]; b0u.i[2] = c[2]; b0u.i[3] = c[3];
                b1u.i[0] = c[4]; b1u.i[1] = c[5]; b1u.i[2] = c[6]; b1u.i[3] = c[7];

                acc = __builtin_amdgcn_mfma_f32_32x32x16_bf16(va0, b0u.v, acc, 0, 0, 0);
                acc = __builtin_amdgcn_mfma_f32_32x32x16_bf16(va1, b1u.v, acc, 0, 0, 0);
            }

            if (ph < 15) {
                const int nxt = cur ^ 1;
                *(uint4*)(&ldsbuf[nxt][kwr]) = kreg;
                *(uint4*)(&ldsbuf[nxt][4096 + vwr]) = vreg;
            }
            __syncthreads();
        }

        l_run += __shfl_xor(l_run, 32);
        float inv = 1.0f / l_run;

        ushort* aob = ao + ((size_t)(bh >> 3) * 256 + (bh & 7) * 32) * 4096 + qbase + l31;
        #pragma unroll
        for (int r = 0; r < 16; ++r) {
            const int d = (r & 3) + 8 * (r >> 2) + 4 * hi;
            aob[(size_t)d * 4096] = f2bf(acc[r] * inv);
        }
    } else {
        // ---- depthwise 7x7 + bilinear upsample ----
        const int bc = blockIdx.x - 1024;
        const int b = bc >> 8, c = bc & 255;
        const ushort* vp = Vb + ((size_t)(b * 8 + (c >> 5)) * 32 + (c & 31)) * 1024;

        float* t   = (float*)smem;              // 38*38*4 = 5776 B
        float* v32 = (float*)(smem + 5776);     // 4096 B
        float* wl  = (float*)(smem + 9872);     // 196 B

        for (int i = tid; i < 38 * 38; i += 256) {
            int yy = i / 38 - 3, xx = i % 38 - 3;
            t[i] = (yy >= 0 && yy < 32 && xx >= 0 && xx < 32) ? bf2f(vp[yy * 32 + xx]) : 0.f;
        }
        if (tid < 49) wl[tid] = Wpe[(size_t)c * 49 + tid];
        __syncthreads();

        const float sc = pe_scale[c], bi = pe_bias[c];
        for (int i = tid; i < 1024; i += 256) {
            int y = i >> 5, x = i & 31;
            float s = 0.f;
            #pragma unroll
            for (int ky = 0; ky < 7; ++ky)
                #pragma unroll
                for (int kx = 0; kx < 7; ++kx)
                    s += t[(y + ky) * 38 + x + kx] * wl[ky * 7 + kx];
            v32[i] = s * sc + bi;
        }
        __syncthreads();

        ushort* op = vpe + (size_t)bc * 4096;
        #pragma unroll
        for (int p = 0; p < 16; ++p) {
            int idx = p * 256 + tid;
            int x = idx & 63, y = idx >> 6;
            float cx = x * 0.5f - 0.25f;
            float cy = y * 0.5f - 0.25f;
            int x0 = (x - 1) >> 1, y0 = (y - 1) >> 1;
            float fx = cx - x0, fy = cy - y0;
            int x0c = max(x0, 0), x1c = min(x0 + 1, 31);
            int y0c = max(y0, 0), y1c = min(y0 + 1, 31);
            float v00 = v32[y0c * 32 + x0c], v01 = v32[y0c * 32 + x1c];
            float v10 = v32[y1c * 32 + x0c], v11 = v32[y1c * 32 + x1c];
            float val = (1.f - fy) * ((1.f - fx) * v00 + fx * v01)
                      + fy * ((1.f - fx) * v10 + fx * v11);
            op[idx] = f2bf(val);
        }
    }
}

// ---------------------------------------------------------------------------
// Output projection, fused with the transpose+add (old `prep`):
// stages S[n][c] = (ao + vpe)^T through LDS (XOR-swizzled), then
// C = Whi*S + Wlo*S.  Block: o=128 x n=64; wave: o=64 (2 acc tiles) x n=32.
// ---------------------------------------------------------------------------
__global__ __launch_bounds__(256, 2) void proj_mfma(
    const ushort* __restrict__ Whi, const ushort* __restrict__ Wlo,
    const ushort* __restrict__ ao, const ushort* __restrict__ vpe,
    const float* __restrict__ scale, const float* __restrict__ bias,
    float* __restrict__ Out)
{
    __shared__ __align__(16) ushort S[64 * 256];   // 32 KB, swizzled [n][c]
    const int tid = threadIdx.x;
    const int b  = blockIdx.z;
    const int n0 = blockIdx.x * 64;        // 64 n-blocks
    const int o0 = blockIdx.y * 128;       // 2 o-blocks

    // ---- stage S[n][c] = ao[c][n] + vpe[c][n] ----
    {
        const int n8 = (tid & 7) * 8;          // local n base (8 rows)
        const int c8 = (tid >> 3) * 8;         // c base (8 rows of source)
        const ushort* ap = ao  + ((size_t)b * 256 + c8) * 4096 + n0 + n8;
        const ushort* vp = vpe + ((size_t)b * 256 + c8) * 4096 + n0 + n8;
        unsigned ow[8][4];                     // [local n j][c-pair rp]
        #pragma unroll
        for (int rp = 0; rp < 4; ++rp) {
            uint4 a0 = *(const uint4*)(ap + (size_t)(2 * rp) * 4096);
            uint4 a1 = *(const uint4*)(ap + (size_t)(2 * rp + 1) * 4096);
            uint4 v0 = *(const uint4*)(vp + (size_t)(2 * rp) * 4096);
            uint4 v1 = *(const uint4*)(vp + (size_t)(2 * rp + 1) * 4096);
            const unsigned* a0u = (const unsigned*)&a0;
            const unsigned* a1u = (const unsigned*)&a1;
            const unsigned* v0u = (const unsigned*)&v0;
            const unsigned* v1u = (const unsigned*)&v1;
            #pragma unroll
            for (int q = 0; q < 4; ++q) {
                float s0lo = __uint_as_float(a0u[q] << 16)
                           + __uint_as_float(v0u[q] << 16);
                float s0hi = __uint_as_float(a0u[q] & 0xffff0000u)
                           + __uint_as_float(v0u[q] & 0xffff0000u);
                float s1lo = __uint_as_float(a1u[q] << 16)
                           + __uint_as_float(v1u[q] << 16);
                float s1hi = __uint_as_float(a1u[q] & 0xffff0000u)
                           + __uint_as_float(v1u[q] & 0xffff0000u);
                unsigned plo, phi;
                asm("v_cvt_pk_bf16_f32 %0, %1, %2" : "=v"(plo) : "v"(s0lo), "v"(s1lo));
                asm("v_cvt_pk_bf16_f32 %0, %1, %2" : "=v"(phi) : "v"(s0hi), "v"(s1hi));
                ow[2 * q][rp]     = plo;
                ow[2 * q + 1][rp] = phi;
            }
        }
        #pragma unroll
        for (int j = 0; j < 8; ++j) {
            const int n = n8 + j;
            const int slot = (((c8 >> 3) ^ (n & 15)) & 31);
            *(uint4*)(&S[n * 256 + (slot << 3)]) = *(const uint4*)&ow[j][0];
        }
    }
    __syncthreads();

    // ---- GEMM ----
    const int w = tid >> 6, l = tid & 63;
    const int l31 = l & 31, hi = l >> 5;
    const int wo = w >> 1, wn = w & 1;     // wave: o-half (64), n-half (32)
    const int ob = o0 + wo * 64;

    const ushort* wh0 = Whi + (size_t)(ob + l31) * 256 + hi * 8;
    const ushort* wh1 = wh0 + (size_t)32 * 256;
    const ushort* wl0 = Wlo + (size_t)(ob + l31) * 256 + hi * 8;
    const ushort* wl1 = wl0 + (size_t)32 * 256;

    const int nloc = wn * 32 + l31;
    const ushort* Srow = &S[nloc * 256];
    const int nsw = nloc & 15;

    f32x16 acc0 = {}, acc1 = {};           // acc0: o in [ob,ob+32), acc1: +32
    #pragma unroll 4
    for (int kk = 0; kk < 256; kk += 16) {
        const int slot = (((kk >> 3) + hi) ^ nsw) & 31;
        bf16x8 av = *(const bf16x8*)(Srow + (slot << 3));
        bf16x8 h0 = *(const bf16x8*)(wh0 + kk);
        bf16x8 h1 = *(const bf16x8*)(wh1 + kk);
        bf16x8 g0 = *(const bf16x8*)(wl0 + kk);
        bf16x8 g1 = *(const bf16x8*)(wl1 + kk);
        acc0 = __builtin_amdgcn_mfma_f32_32x32x16_bf16(h0, av, acc0, 0, 0, 0);
        acc1 = __builtin_amdgcn_mfma_f32_32x32x16_bf16(h1, av, acc1, 0, 0, 0);
        acc0 = __builtin_amdgcn_mfma_f32_32x32x16_bf16(g0, av, acc0, 0, 0, 0);
        acc1 = __builtin_amdgcn_mfma_f32_32x32x16_bf16(g1, av, acc1, 0, 0, 0);
    }

    float* Ob = Out + (size_t)b * 256 * 4096 + n0 + wn * 32 + l31;
    #pragma unroll
    for (int r = 0; r < 16; ++r) {
        const int dr = (r & 3) + 8 * (r >> 2) + 4 * hi;
        const int oA = ob + dr, oB = ob + 32 + dr;
        Ob[(size_t)oA * 4096] = acc0[r] * scale[oA] + bias[oA];
        Ob[(size_t)oB * 4096] = acc1[r] * scale[oB] + bias[oB];
    }
}

// ---------------------------------------------------------------------------
extern "C" void kernel_launch(void* const* d_in, const int* in_sizes, int n_in,
                              void* d_out, int out_size, void* d_ws, size_t ws_size,
                              hipStream_t stream)
{
    const float* x        = (const float*)d_in[0];
    const float* upper    = (const float*)d_in[1];
    const float* Wq       = (const float*)d_in[2];
    const float* q_scale  = (const float*)d_in[3];
    const float* q_bias   = (const float*)d_in[4];
    const float* Wkv      = (const float*)d_in[5];
    const float* kv_scale = (const float*)d_in[6];
    const float* kv_bias  = (const float*)d_in[7];
    const float* Wpe      = (const float*)d_in[8];
    const float* pe_scale = (const float*)d_in[9];
    const float* pe_bias  = (const float*)d_in[10];
    const float* Wproj    = (const float*)d_in[11];
    const float* proj_scale = (const float*)d_in[12];
    const float* proj_bias  = (const float*)d_in[13];
    float* out = (float*)d_out;

    ushort* Qb   = (ushort*)d_ws;                           // 8.39 MB
    ushort* Kb   = Qb + (size_t)32 * 4096 * 32;             // 2.10 MB
    ushort* Vb   = Kb + (size_t)32 * 1024 * 32;             // 2.10 MB
    ushort* ao   = Vb + (size_t)32 * 1024 * 32;             // 8.39 MB bf16 [b][256][4096]
    ushort* vpe  = ao + (size_t)Bq * DIM * Nq;              // 8.39 MB bf16 [b][256][4096]
    ushort* Wqb  = vpe + (size_t)Bq * DIM * Nq;             // 128 KB
    ushort* Wkvb = Wqb + 256 * 256;                         // 256 KB
    ushort* Wph  = Wkvb + 512 * 256;                        // 128 KB
    ushort* Wpl  = Wph + 256 * 256;                         // 128 KB

    const float qmult = 0.17677669529663687f * 1.4426950408889634f; // qscale*log2e

    prepro<<<dim3(512), 256, 0, stream>>>(Wq, Wqb, Wkv, Wkvb, Wproj, Wph, Wpl);

    qkv_mfma<<<dim3(768), 256, 0, stream>>>(Wqb, x, q_scale, q_bias, qmult,
                                            Wkvb, upper, kv_scale, kv_bias,
                                            Qb, Kb, Vb);

    attn_dw<<<dim3(2048), 256, 0, stream>>>(Qb, Kb, Vb, ao,
                                            Wpe, pe_scale, pe_bias, vpe);

    proj_mfma<<<dim3(64, 2, 4), 256, 0, stream>>>(Wph, Wpl, ao, vpe,
                                                  proj_scale, proj_bias, out);
}

// Round 5
// 81.779 us; speedup vs baseline: 1.1021x; 1.0085x over previous
//
#include <hip/hip_runtime.h>
#include <hip/hip_bf16.h>

#define DIM 256
#define NHEADS 8
#define HDIM 32
#define Bq 4
#define Nq 4096   // 64*64
#define Nu 1024   // 32*32

typedef __attribute__((ext_vector_type(8))) short bf16x8;
typedef __attribute__((ext_vector_type(16))) float f32x16;
typedef __attribute__((ext_vector_type(4))) unsigned short us4;

__device__ __forceinline__ ushort f2bf(float x) {
    union { float f; unsigned u; } v; v.f = x;
    unsigned r = v.u + 0x7fffu + ((v.u >> 16) & 1u);
    return (ushort)(r >> 16);
}
__device__ __forceinline__ float bf2f(ushort u) {
    union { unsigned u; float f; } v; v.u = ((unsigned)u) << 16;
    return v.f;
}

// ---------------------------------------------------------------------------
// prepro: weight casts only.  grid 512 x 256 threads.
// ---------------------------------------------------------------------------
__global__ __launch_bounds__(256) void prepro(
    const float* __restrict__ Wq, ushort* __restrict__ Oq,
    const float* __restrict__ Wkv, ushort* __restrict__ Okv,
    const float* __restrict__ Wp, ushort* __restrict__ Oph, ushort* __restrict__ Opl)
{
    const int i = blockIdx.x * 256 + threadIdx.x;
    if (i < 65536) {
        Oq[i] = f2bf(Wq[i]);
        float w = Wp[i];
        ushort h = f2bf(w);
        Oph[i] = h;
        Opl[i] = f2bf(w - bf2f(h));
    }
    Okv[i] = f2bf(Wkv[i]);
}

// ---------------------------------------------------------------------------
// qkv (fused transpose + GEMM): blocks [0,512): Q (128 n-blocks x 4 b);
// [512,768): KV (32 n x 2 oh x 4 b).
// Stages a [32 n][256 c] bf16 tile of fp32 input through swizzled LDS
// (in-register cvt_pk transpose), then each wave computes 64 output rows:
// Q: heads 2w,2w+1; KV: head oh*4+w's K (transposed out) + V (direct out).
// ---------------------------------------------------------------------------
__global__ __launch_bounds__(256, 4) void qkv_mfma(
    const ushort* __restrict__ Wqb, const float* __restrict__ x,
    const float* __restrict__ q_scale, const float* __restrict__ q_bias, float qmult,
    const ushort* __restrict__ Wkvb, const float* __restrict__ upper,
    const float* __restrict__ kv_scale, const float* __restrict__ kv_bias,
    ushort* __restrict__ Qb, ushort* __restrict__ Kb, ushort* __restrict__ Vb)
{
    __shared__ __align__(16) ushort S[32 * 256];   // 16 KB, swizzled [n][c]
    const int id = blockIdx.x;
    const int tid = threadIdx.x;

    const float* In; int N, n0, b, oh; bool isQ;
    if (id < 512) {
        isQ = true; In = x; N = 4096;
        n0 = (id & 127) * 32; b = id >> 7; oh = 0;
    } else {
        int q = id - 512;
        isQ = false; In = upper; N = 1024;
        n0 = (q & 31) * 32; oh = (q >> 5) & 1; b = q >> 6;
    }

    // ---- stage S[n][c] = bf16(In[c][n]) ----
    {
        const int n4 = (tid & 7) * 4, c8 = (tid >> 3) * 8;
        const float* ip = In + ((size_t)b * 256 + c8) * N + n0 + n4;
        unsigned ow[4][4];                 // [local n j][c-pair rp]
        #pragma unroll
        for (int rp = 0; rp < 4; ++rp) {
            float4 f0 = *(const float4*)(ip + (size_t)(2 * rp) * N);
            float4 f1 = *(const float4*)(ip + (size_t)(2 * rp + 1) * N);
            asm("v_cvt_pk_bf16_f32 %0, %1, %2" : "=v"(ow[0][rp]) : "v"(f0.x), "v"(f1.x));
            asm("v_cvt_pk_bf16_f32 %0, %1, %2" : "=v"(ow[1][rp]) : "v"(f0.y), "v"(f1.y));
            asm("v_cvt_pk_bf16_f32 %0, %1, %2" : "=v"(ow[2][rp]) : "v"(f0.z), "v"(f1.z));
            asm("v_cvt_pk_bf16_f32 %0, %1, %2" : "=v"(ow[3][rp]) : "v"(f0.w), "v"(f1.w));
        }
        #pragma unroll
        for (int j = 0; j < 4; ++j) {
            const int n = n4 + j;
            const int slot = ((c8 >> 3) ^ (n & 15)) & 31;
            *(uint4*)(&S[n * 256 + (slot << 3)]) = *(const uint4*)&ow[j][0];
        }
    }
    __syncthreads();

    const int w = tid >> 6, l = tid & 63;
    const int l31 = l & 31, hi = l >> 5;
    const int nsw = l31 & 15;
    const ushort* Srow = &S[l31 * 256];

    if (isQ) {
        const ushort* w0 = Wqb + (size_t)(w * 64 + l31) * 256 + hi * 8;
        const ushort* w1 = w0 + (size_t)32 * 256;
        f32x16 acc0 = {}, acc1 = {};
        #pragma unroll 8
        for (int kk = 0; kk < 256; kk += 16) {
            const int slot = (((kk >> 3) + hi) ^ nsw) & 31;
            bf16x8 av = *(const bf16x8*)(Srow + (slot << 3));
            bf16x8 h0 = *(const bf16x8*)(w0 + kk);
            bf16x8 h1 = *(const bf16x8*)(w1 + kk);
            acc0 = __builtin_amdgcn_mfma_f32_32x32x16_bf16(av, h0, acc0, 0, 0, 0);
            acc1 = __builtin_amdgcn_mfma_f32_32x32x16_bf16(av, h1, acc1, 0, 0, 0);
        }
        #pragma unroll
        for (int t = 0; t < 2; ++t) {
            const f32x16 a = t ? acc1 : acc0;
            const int orow = w * 64 + t * 32 + l31;
            const float sc = q_scale[orow] * qmult;
            const float bi = q_bias[orow] * qmult;
            const int bh = b * 8 + 2 * w + t;
            ushort* Oa = Qb + ((size_t)bh * 4096) * 32 + l31;
            #pragma unroll
            for (int r = 0; r < 16; ++r) {
                const int dn = (r & 3) + 8 * (r >> 2) + 4 * hi;
                Oa[(size_t)(n0 + dn) * 32] = f2bf(a[r] * sc + bi);
            }
        }
    } else {
        const int h = oh * 4 + w;
        const ushort* wk = Wkvb + (size_t)(h * 64 + l31) * 256 + hi * 8;
        const ushort* wv = wk + (size_t)32 * 256;
        f32x16 accK = {}, accV = {};
        #pragma unroll 8
        for (int kk = 0; kk < 256; kk += 16) {
            const int slot = (((kk >> 3) + hi) ^ nsw) & 31;
            bf16x8 av = *(const bf16x8*)(Srow + (slot << 3));
            bf16x8 k0 = *(const bf16x8*)(wk + kk);
            bf16x8 v0 = *(const bf16x8*)(wv + kk);
            accK = __builtin_amdgcn_mfma_f32_32x32x16_bf16(av, k0, accK, 0, 0, 0);
            accV = __builtin_amdgcn_mfma_f32_32x32x16_bf16(v0, av, accV, 0, 0, 0);
        }
        const int bh = b * 8 + h;
        {
            const float sc = kv_scale[h * 64 + l31];
            const float bi = kv_bias[h * 64 + l31];
            ushort* Oa = Kb + ((size_t)bh * 1024) * 32 + l31;
            #pragma unroll
            for (int r = 0; r < 16; ++r) {
                const int dn = (r & 3) + 8 * (r >> 2) + 4 * hi;
                Oa[(size_t)(n0 + dn) * 32] = f2bf(accK[r] * sc + bi);
            }
        }
        {
            ushort* Ob = Vb + (size_t)bh * 32 * 1024;
            #pragma unroll
            for (int r = 0; r < 16; ++r) {
                const int dr = (r & 3) + 8 * (r >> 2) + 4 * hi;
                const float sc = kv_scale[h * 64 + 32 + dr];
                const float bi = kv_bias[h * 64 + 32 + dr];
                Ob[(size_t)dr * 1024 + n0 + l31] = f2bf(accV[r] * sc + bi);
            }
        }
    }
}

// ---------------------------------------------------------------------------
// attn_dw (merged): blocks [0,1024): flash attention (round-8 structure,
// bf16 output); [1024,2048): depthwise 7x7 + upsample (bf16 output).
// Shared 16KB LDS union.
// ---------------------------------------------------------------------------
__global__ __launch_bounds__(256, 4) void attn_dw(
    const ushort* __restrict__ Qb, const ushort* __restrict__ Kt,
    const ushort* __restrict__ Vb, ushort* __restrict__ ao,
    const float* __restrict__ Wpe, const float* __restrict__ pe_scale,
    const float* __restrict__ pe_bias, ushort* __restrict__ vpe)
{
    __shared__ __align__(16) unsigned char smem[16384];
    const int tid = threadIdx.x;

    if (blockIdx.x < 1024) {
        // ---- attention ----
        const int w = tid >> 6, l = tid & 63;
        const int l31 = l & 31, hi = l >> 5;
        const int lid = blockIdx.x;
        const int j = lid >> 3;
        const int bh = (lid & 7) * 4 + (j >> 5);
        const int qbase = (j & 31) * 128 + w * 32;

        unsigned char (*ldsbuf)[8192] = (unsigned char(*)[8192])smem;

        const ushort* Qp = Qb + ((size_t)bh * 4096 + qbase) * 32;
        const unsigned char* Kg = (const unsigned char*)(Kt + (size_t)bh * 1024 * 32);
        const unsigned char* Vg = (const unsigned char*)(Vb + (size_t)bh * 32 * 1024);

        const bf16x8 qb0 = *(const bf16x8*)(Qp + (size_t)l31 * 32 + hi * 8);
        const bf16x8 qb1 = *(const bf16x8*)(Qp + (size_t)l31 * 32 + 16 + hi * 8);

        const int kr = tid >> 2, kc = tid & 3;
        const int vd = tid >> 3, vc = tid & 7;
        const int kwr = (kr * 64 + kc * 16) ^ ((kr & 7) << 4);
        const int vwr = vd * 128 + ((vc ^ (vd & 7)) << 4);

        f32x16 acc = {};
        float l_run = 0.f;

        uint4 kreg = *(const uint4*)(Kg + kr * 64 + kc * 16);
        uint4 vreg = *(const uint4*)(Vg + vd * 2048 + vc * 16);
        *(uint4*)(&ldsbuf[0][kwr]) = kreg;
        *(uint4*)(&ldsbuf[0][4096 + vwr]) = vreg;
        __syncthreads();

        for (int ph = 0; ph < 16; ++ph) {
            const int cur = ph & 1;
            if (ph < 15) {
                const size_t koff = (size_t)(ph + 1) * 4096;
                const int    voff = (ph + 1) * 128;
                kreg = *(const uint4*)(Kg + koff + kr * 64 + kc * 16);
                vreg = *(const uint4*)(Vg + (size_t)vd * 2048 + voff + vc * 16);
            }
            const unsigned char* Kl = &ldsbuf[cur][0];
            const unsigned char* Vl = &ldsbuf[cur][4096];

            #pragma unroll
            for (int s = 0; s < 2; ++s) {
                const int r = s * 32 + l31;
                bf16x8 ka0 = *(const bf16x8*)(Kl + ((r * 64 + hi * 16) ^ ((r & 7) << 4)));
                bf16x8 ka1 = *(const bf16x8*)(Kl + ((r * 64 + 32 + hi * 16) ^ ((r & 7) << 4)));
                bf16x8 va0 = *(const bf16x8*)(Vl + l31 * 128 + (((s * 4 + hi)     ^ (l31 & 7)) << 4));
                bf16x8 va1 = *(const bf16x8*)(Vl + l31 * 128 + (((s * 4 + 2 + hi) ^ (l31 & 7)) << 4));

                f32x16 sv = {};
                sv = __builtin_amdgcn_mfma_f32_32x32x16_bf16(ka0, qb0, sv, 0, 0, 0);
                sv = __builtin_amdgcn_mfma_f32_32x32x16_bf16(ka1, qb1, sv, 0, 0, 0);

                float p[16];
                #pragma unroll
                for (int r2 = 0; r2 < 16; ++r2) p[r2] = __builtin_amdgcn_exp2f(sv[r2]);
                l_run += (((p[0] + p[1]) + (p[2] + p[3])) + ((p[4] + p[5]) + (p[6] + p[7])))
                       + (((p[8] + p[9]) + (p[10] + p[11])) + ((p[12] + p[13]) + (p[14] + p[15])));

                int c[8];
                #pragma unroll
                for (int i = 0; i < 8; ++i)
                    asm("v_cvt_pk_bf16_f32 %0, %1, %2" : "=v"(c[i]) : "v"(p[2 * i]), "v"(p[2 * i + 1]));
                asm("v_permlane32_swap_b32 %0, %1" : "+v"(c[0]), "+v"(c[2]));
                asm("v_permlane32_swap_b32 %0, %1" : "+v"(c[1]), "+v"(c[3]));
                asm("v_permlane32_swap_b32 %0, %1" : "+v"(c[4]), "+v"(c[6]));
                asm("v_permlane32_swap_b32 %0, %1" : "+v"(c[5]), "+v"(c[7]));

                union { int i[4]; bf16x8 v; } b0u, b1u;
                b0u.i[0] = c[0]; b0u.i[1] = c[1]; b0u.i[2] = c[2]; b0u.i[3] = c[3];
                b1u.i[0] = c[4]; b1u.i[1] = c[5]; b1u.i[2] = c[6]; b1u.i[3] = c[7];

                acc = __builtin_amdgcn_mfma_f32_32x32x16_bf16(va0, b0u.v, acc, 0, 0, 0);
                acc = __builtin_amdgcn_mfma_f32_32x32x16_bf16(va1, b1u.v, acc, 0, 0, 0);
            }

            if (ph < 15) {
                const int nxt = cur ^ 1;
                *(uint4*)(&ldsbuf[nxt][kwr]) = kreg;
                *(uint4*)(&ldsbuf[nxt][4096 + vwr]) = vreg;
            }
            __syncthreads();
        }

        l_run += __shfl_xor(l_run, 32);
        float inv = 1.0f / l_run;

        ushort* aob = ao + ((size_t)(bh >> 3) * 256 + (bh & 7) * 32) * 4096 + qbase + l31;
        #pragma unroll
        for (int r = 0; r < 16; ++r) {
            const int d = (r & 3) + 8 * (r >> 2) + 4 * hi;
            aob[(size_t)d * 4096] = f2bf(acc[r] * inv);
        }
    } else {
        // ---- depthwise 7x7 + bilinear upsample ----
        const int bc = blockIdx.x - 1024;
        const int b = bc >> 8, c = bc & 255;
        const ushort* vp = Vb + ((size_t)(b * 8 + (c >> 5)) * 32 + (c & 31)) * 1024;

        float* t   = (float*)smem;              // 38*38*4 = 5776 B
        float* v32 = (float*)(smem + 5776);     // 4096 B
        float* wl  = (float*)(smem + 9872);     // 196 B

        for (int i = tid; i < 38 * 38; i += 256) {
            int yy = i / 38 - 3, xx = i % 38 - 3;
            t[i] = (yy >= 0 && yy < 32 && xx >= 0 && xx < 32) ? bf2f(vp[yy * 32 + xx]) : 0.f;
        }
        if (tid < 49) wl[tid] = Wpe[(size_t)c * 49 + tid];
        __syncthreads();

        const float sc = pe_scale[c], bi = pe_bias[c];
        for (int i = tid; i < 1024; i += 256) {
            int y = i >> 5, x = i & 31;
            float s = 0.f;
            #pragma unroll
            for (int ky = 0; ky < 7; ++ky)
                #pragma unroll
                for (int kx = 0; kx < 7; ++kx)
                    s += t[(y + ky) * 38 + x + kx] * wl[ky * 7 + kx];
            v32[i] = s * sc + bi;
        }
        __syncthreads();

        ushort* op = vpe + (size_t)bc * 4096;
        #pragma unroll
        for (int p = 0; p < 16; ++p) {
            int idx = p * 256 + tid;
            int x = idx & 63, y = idx >> 6;
            float cx = x * 0.5f - 0.25f;
            float cy = y * 0.5f - 0.25f;
            int x0 = (x - 1) >> 1, y0 = (y - 1) >> 1;
            float fx = cx - x0, fy = cy - y0;
            int x0c = max(x0, 0), x1c = min(x0 + 1, 31);
            int y0c = max(y0, 0), y1c = min(y0 + 1, 31);
            float v00 = v32[y0c * 32 + x0c], v01 = v32[y0c * 32 + x1c];
            float v10 = v32[y1c * 32 + x0c], v11 = v32[y1c * 32 + x1c];
            float val = (1.f - fy) * ((1.f - fx) * v00 + fx * v01)
                      + fy * ((1.f - fx) * v10 + fx * v11);
            op[idx] = f2bf(val);
        }
    }
}

// ---------------------------------------------------------------------------
// Output projection (fused transpose+add): 512-thread blocks, each covering
// ALL o=256 for one 64-wide n-tile, so ao/vpe are staged exactly once.
// 8 waves: wave w -> o-quarter (w&3)*64, n-half (w>>2)*32.
// ---------------------------------------------------------------------------
__global__ __launch_bounds__(512, 2) void proj_mfma(
    const ushort* __restrict__ Whi, const ushort* __restrict__ Wlo,
    const ushort* __restrict__ ao, const ushort* __restrict__ vpe,
    const float* __restrict__ scale, const float* __restrict__ bias,
    float* __restrict__ Out)
{
    __shared__ __align__(16) ushort S[64 * 256];   // 32 KB, swizzled [n][c]
    const int tid = threadIdx.x;
    const int b  = blockIdx.z;
    const int n0 = blockIdx.x * 64;        // 64 n-blocks

    // ---- stage S[n][c] = ao[c][n] + vpe[c][n] (512 threads, 4n x 8c each) ----
    {
        const int n4 = (tid & 15) * 4;         // local n base (4 rows)
        const int c8 = (tid >> 4) * 8;         // c base (8 source rows)
        const ushort* ap = ao  + ((size_t)b * 256 + c8) * 4096 + n0 + n4;
        const ushort* vp = vpe + ((size_t)b * 256 + c8) * 4096 + n0 + n4;
        unsigned ow[4][4];                     // [local n j][c-pair rp]
        #pragma unroll
        for (int rp = 0; rp < 4; ++rp) {
            uint2 a0 = *(const uint2*)(ap + (size_t)(2 * rp) * 4096);
            uint2 a1 = *(const uint2*)(ap + (size_t)(2 * rp + 1) * 4096);
            uint2 v0 = *(const uint2*)(vp + (size_t)(2 * rp) * 4096);
            uint2 v1 = *(const uint2*)(vp + (size_t)(2 * rp + 1) * 4096);
            const unsigned a0u[2] = { a0.x, a0.y };
            const unsigned a1u[2] = { a1.x, a1.y };
            const unsigned v0u[2] = { v0.x, v0.y };
            const unsigned v1u[2] = { v1.x, v1.y };
            #pragma unroll
            for (int q = 0; q < 2; ++q) {
                float s0lo = __uint_as_float(a0u[q] << 16)
                           + __uint_as_float(v0u[q] << 16);
                float s0hi = __uint_as_float(a0u[q] & 0xffff0000u)
                           + __uint_as_float(v0u[q] & 0xffff0000u);
                float s1lo = __uint_as_float(a1u[q] << 16)
                           + __uint_as_float(v1u[q] << 16);
                float s1hi = __uint_as_float(a1u[q] & 0xffff0000u)
                           + __uint_as_float(v1u[q] & 0xffff0000u);
                unsigned plo, phi;
                asm("v_cvt_pk_bf16_f32 %0, %1, %2" : "=v"(plo) : "v"(s0lo), "v"(s1lo));
                asm("v_cvt_pk_bf16_f32 %0, %1, %2" : "=v"(phi) : "v"(s0hi), "v"(s1hi));
                ow[2 * q][rp]     = plo;
                ow[2 * q + 1][rp] = phi;
            }
        }
        #pragma unroll
        for (int j = 0; j < 4; ++j) {
            const int n = n4 + j;
            const int slot = (((c8 >> 3) ^ (n & 15)) & 31);
            *(uint4*)(&S[n * 256 + (slot << 3)]) = *(const uint4*)&ow[j][0];
        }
    }
    __syncthreads();

    // ---- GEMM ----
    const int w = tid >> 6, l = tid & 63;
    const int l31 = l & 31, hi = l >> 5;
    const int wo = w & 3, wn = w >> 2;     // o-quarter (64), n-half (32)
    const int ob = wo * 64;

    const ushort* wh0 = Whi + (size_t)(ob + l31) * 256 + hi * 8;
    const ushort* wh1 = wh0 + (size_t)32 * 256;
    const ushort* wl0 = Wlo + (size_t)(ob + l31) * 256 + hi * 8;
    const ushort* wl1 = wl0 + (size_t)32 * 256;

    const int nloc = wn * 32 + l31;
    const ushort* Srow = &S[nloc * 256];
    const int nsw = nloc & 15;

    f32x16 acc0 = {}, acc1 = {};           // acc0: o in [ob,ob+32), acc1: +32
    #pragma unroll 4
    for (int kk = 0; kk < 256; kk += 16) {
        const int slot = (((kk >> 3) + hi) ^ nsw) & 31;
        bf16x8 av = *(const bf16x8*)(Srow + (slot << 3));
        bf16x8 h0 = *(const bf16x8*)(wh0 + kk);
        bf16x8 h1 = *(const bf16x8*)(wh1 + kk);
        bf16x8 g0 = *(const bf16x8*)(wl0 + kk);
        bf16x8 g1 = *(const bf16x8*)(wl1 + kk);
        acc0 = __builtin_amdgcn_mfma_f32_32x32x16_bf16(h0, av, acc0, 0, 0, 0);
        acc1 = __builtin_amdgcn_mfma_f32_32x32x16_bf16(h1, av, acc1, 0, 0, 0);
        acc0 = __builtin_amdgcn_mfma_f32_32x32x16_bf16(g0, av, acc0, 0, 0, 0);
        acc1 = __builtin_amdgcn_mfma_f32_32x32x16_bf16(g1, av, acc1, 0, 0, 0);
    }

    float* Ob = Out + (size_t)b * 256 * 4096 + n0 + wn * 32 + l31;
    #pragma unroll
    for (int r = 0; r < 16; ++r) {
        const int dr = (r & 3) + 8 * (r >> 2) + 4 * hi;
        const int oA = ob + dr, oB = ob + 32 + dr;
        Ob[(size_t)oA * 4096] = acc0[r] * scale[oA] + bias[oA];
        Ob[(size_t)oB * 4096] = acc1[r] * scale[oB] + bias[oB];
    }
}

// ---------------------------------------------------------------------------
extern "C" void kernel_launch(void* const* d_in, const int* in_sizes, int n_in,
                              void* d_out, int out_size, void* d_ws, size_t ws_size,
                              hipStream_t stream)
{
    const float* x        = (const float*)d_in[0];
    const float* upper    = (const float*)d_in[1];
    const float* Wq       = (const float*)d_in[2];
    const float* q_scale  = (const float*)d_in[3];
    const float* q_bias   = (const float*)d_in[4];
    const float* Wkv      = (const float*)d_in[5];
    const float* kv_scale = (const float*)d_in[6];
    const float* kv_bias  = (const float*)d_in[7];
    const float* Wpe      = (const float*)d_in[8];
    const float* pe_scale = (const float*)d_in[9];
    const float* pe_bias  = (const float*)d_in[10];
    const float* Wproj    = (const float*)d_in[11];
    const float* proj_scale = (const float*)d_in[12];
    const float* proj_bias  = (const float*)d_in[13];
    float* out = (float*)d_out;

    ushort* Qb   = (ushort*)d_ws;                           // 8.39 MB
    ushort* Kb   = Qb + (size_t)32 * 4096 * 32;             // 2.10 MB
    ushort* Vb   = Kb + (size_t)32 * 1024 * 32;             // 2.10 MB
    ushort* ao   = Vb + (size_t)32 * 1024 * 32;             // 8.39 MB bf16 [b][256][4096]
    ushort* vpe  = ao + (size_t)Bq * DIM * Nq;              // 8.39 MB bf16 [b][256][4096]
    ushort* Wqb  = vpe + (size_t)Bq * DIM * Nq;             // 128 KB
    ushort* Wkvb = Wqb + 256 * 256;                         // 256 KB
    ushort* Wph  = Wkvb + 512 * 256;                        // 128 KB
    ushort* Wpl  = Wph + 256 * 256;                         // 128 KB

    const float qmult = 0.17677669529663687f * 1.4426950408889634f; // qscale*log2e

    prepro<<<dim3(512), 256, 0, stream>>>(Wq, Wqb, Wkv, Wkvb, Wproj, Wph, Wpl);

    qkv_mfma<<<dim3(768), 256, 0, stream>>>(Wqb, x, q_scale, q_bias, qmult,
                                            Wkvb, upper, kv_scale, kv_bias,
                                            Qb, Kb, Vb);

    attn_dw<<<dim3(2048), 256, 0, stream>>>(Qb, Kb, Vb, ao,
                                            Wpe, pe_scale, pe_bias, vpe);

    proj_mfma<<<dim3(64, 1, 4), 512, 0, stream>>>(Wph, Wpl, ao, vpe,
                                                  proj_scale, proj_bias, out);
}

// Round 6
// 78.912 us; speedup vs baseline: 1.1421x; 1.0363x over previous
//
#include <hip/hip_runtime.h>
#include <hip/hip_bf16.h>

#define DIM 256
#define NHEADS 8
#define HDIM 32
#define Bq 4
#define Nq 4096   // 64*64
#define Nu 1024   // 32*32

typedef __attribute__((ext_vector_type(8))) short bf16x8;
typedef __attribute__((ext_vector_type(16))) float f32x16;
typedef __attribute__((ext_vector_type(4))) unsigned short us4;

__device__ __forceinline__ ushort f2bf(float x) {
    union { float f; unsigned u; } v; v.f = x;
    unsigned r = v.u + 0x7fffu + ((v.u >> 16) & 1u);
    return (ushort)(r >> 16);
}
__device__ __forceinline__ float bf2f(ushort u) {
    union { unsigned u; float f; } v; v.u = ((unsigned)u) << 16;
    return v.f;
}
__device__ __forceinline__ float bfu2f(unsigned lo16shifted) {
    union { unsigned u; float f; } v; v.u = lo16shifted;
    return v.f;
}

// ---------------------------------------------------------------------------
// prepro: weight casts only.  grid 512 x 256 threads.
// ---------------------------------------------------------------------------
__global__ __launch_bounds__(256) void prepro(
    const float* __restrict__ Wq, ushort* __restrict__ Oq,
    const float* __restrict__ Wkv, ushort* __restrict__ Okv,
    const float* __restrict__ Wp, ushort* __restrict__ Oph, ushort* __restrict__ Opl)
{
    const int i = blockIdx.x * 256 + threadIdx.x;
    if (i < 65536) {
        Oq[i] = f2bf(Wq[i]);
        float w = Wp[i];
        ushort h = f2bf(w);
        Oph[i] = h;
        Opl[i] = f2bf(w - bf2f(h));
    }
    Okv[i] = f2bf(Wkv[i]);
}

// ---------------------------------------------------------------------------
// qkv (fused transpose + GEMM): blocks [0,512): Q (128 n-blocks x 4 b);
// [512,768): KV (32 n x 2 oh x 4 b).
// Stages a [32 n][256 c] bf16 tile of fp32 input through swizzled LDS
// (in-register cvt_pk transpose), then each wave computes 64 output rows:
// Q: heads 2w,2w+1; KV: head oh*4+w's K (transposed out) + V (direct out).
// ---------------------------------------------------------------------------
__global__ __launch_bounds__(256, 4) void qkv_mfma(
    const ushort* __restrict__ Wqb, const float* __restrict__ x,
    const float* __restrict__ q_scale, const float* __restrict__ q_bias, float qmult,
    const ushort* __restrict__ Wkvb, const float* __restrict__ upper,
    const float* __restrict__ kv_scale, const float* __restrict__ kv_bias,
    ushort* __restrict__ Qb, ushort* __restrict__ Kb, ushort* __restrict__ Vb)
{
    __shared__ __align__(16) ushort S[32 * 256];   // 16 KB, swizzled [n][c]
    const int id = blockIdx.x;
    const int tid = threadIdx.x;

    const float* In; int N, n0, b, oh; bool isQ;
    if (id < 512) {
        isQ = true; In = x; N = 4096;
        n0 = (id & 127) * 32; b = id >> 7; oh = 0;
    } else {
        int q = id - 512;
        isQ = false; In = upper; N = 1024;
        n0 = (q & 31) * 32; oh = (q >> 5) & 1; b = q >> 6;
    }

    // ---- stage S[n][c] = bf16(In[c][n]) ----
    {
        const int n4 = (tid & 7) * 4, c8 = (tid >> 3) * 8;
        const float* ip = In + ((size_t)b * 256 + c8) * N + n0 + n4;
        unsigned ow[4][4];                 // [local n j][c-pair rp]
        #pragma unroll
        for (int rp = 0; rp < 4; ++rp) {
            float4 f0 = *(const float4*)(ip + (size_t)(2 * rp) * N);
            float4 f1 = *(const float4*)(ip + (size_t)(2 * rp + 1) * N);
            asm("v_cvt_pk_bf16_f32 %0, %1, %2" : "=v"(ow[0][rp]) : "v"(f0.x), "v"(f1.x));
            asm("v_cvt_pk_bf16_f32 %0, %1, %2" : "=v"(ow[1][rp]) : "v"(f0.y), "v"(f1.y));
            asm("v_cvt_pk_bf16_f32 %0, %1, %2" : "=v"(ow[2][rp]) : "v"(f0.z), "v"(f1.z));
            asm("v_cvt_pk_bf16_f32 %0, %1, %2" : "=v"(ow[3][rp]) : "v"(f0.w), "v"(f1.w));
        }
        #pragma unroll
        for (int j = 0; j < 4; ++j) {
            const int n = n4 + j;
            const int slot = ((c8 >> 3) ^ (n & 15)) & 31;
            *(uint4*)(&S[n * 256 + (slot << 3)]) = *(const uint4*)&ow[j][0];
        }
    }
    __syncthreads();

    const int w = tid >> 6, l = tid & 63;
    const int l31 = l & 31, hi = l >> 5;
    const int nsw = l31 & 15;
    const ushort* Srow = &S[l31 * 256];

    if (isQ) {
        const ushort* w0 = Wqb + (size_t)(w * 64 + l31) * 256 + hi * 8;
        const ushort* w1 = w0 + (size_t)32 * 256;
        f32x16 acc0 = {}, acc1 = {};
        #pragma unroll 8
        for (int kk = 0; kk < 256; kk += 16) {
            const int slot = (((kk >> 3) + hi) ^ nsw) & 31;
            bf16x8 av = *(const bf16x8*)(Srow + (slot << 3));
            bf16x8 h0 = *(const bf16x8*)(w0 + kk);
            bf16x8 h1 = *(const bf16x8*)(w1 + kk);
            acc0 = __builtin_amdgcn_mfma_f32_32x32x16_bf16(av, h0, acc0, 0, 0, 0);
            acc1 = __builtin_amdgcn_mfma_f32_32x32x16_bf16(av, h1, acc1, 0, 0, 0);
        }
        #pragma unroll
        for (int t = 0; t < 2; ++t) {
            const f32x16 a = t ? acc1 : acc0;
            const int orow = w * 64 + t * 32 + l31;
            const float sc = q_scale[orow] * qmult;
            const float bi = q_bias[orow] * qmult;
            const int bh = b * 8 + 2 * w + t;
            ushort* Oa = Qb + ((size_t)bh * 4096) * 32 + l31;
            #pragma unroll
            for (int r = 0; r < 16; ++r) {
                const int dn = (r & 3) + 8 * (r >> 2) + 4 * hi;
                Oa[(size_t)(n0 + dn) * 32] = f2bf(a[r] * sc + bi);
            }
        }
    } else {
        const int h = oh * 4 + w;
        const ushort* wk = Wkvb + (size_t)(h * 64 + l31) * 256 + hi * 8;
        const ushort* wv = wk + (size_t)32 * 256;
        f32x16 accK = {}, accV = {};
        #pragma unroll 8
        for (int kk = 0; kk < 256; kk += 16) {
            const int slot = (((kk >> 3) + hi) ^ nsw) & 31;
            bf16x8 av = *(const bf16x8*)(Srow + (slot << 3));
            bf16x8 k0 = *(const bf16x8*)(wk + kk);
            bf16x8 v0 = *(const bf16x8*)(wv + kk);
            accK = __builtin_amdgcn_mfma_f32_32x32x16_bf16(av, k0, accK, 0, 0, 0);
            accV = __builtin_amdgcn_mfma_f32_32x32x16_bf16(v0, av, accV, 0, 0, 0);
        }
        const int bh = b * 8 + h;
        {
            const float sc = kv_scale[h * 64 + l31];
            const float bi = kv_bias[h * 64 + l31];
            ushort* Oa = Kb + ((size_t)bh * 1024) * 32 + l31;
            #pragma unroll
            for (int r = 0; r < 16; ++r) {
                const int dn = (r & 3) + 8 * (r >> 2) + 4 * hi;
                Oa[(size_t)(n0 + dn) * 32] = f2bf(accK[r] * sc + bi);
            }
        }
        {
            ushort* Ob = Vb + (size_t)bh * 32 * 1024;
            #pragma unroll
            for (int r = 0; r < 16; ++r) {
                const int dr = (r & 3) + 8 * (r >> 2) + 4 * hi;
                const float sc = kv_scale[h * 64 + 32 + dr];
                const float bi = kv_bias[h * 64 + 32 + dr];
                Ob[(size_t)dr * 1024 + n0 + l31] = f2bf(accV[r] * sc + bi);
            }
        }
    }
}

// ---------------------------------------------------------------------------
// attn_dw (merged): blocks [0,1024): flash attention (bf16 output);
// [1024,2048): depthwise 7x7 -> 32x32 fp32 field (upsample moved to proj).
// ---------------------------------------------------------------------------
__global__ __launch_bounds__(256, 4) void attn_dw(
    const ushort* __restrict__ Qb, const ushort* __restrict__ Kt,
    const ushort* __restrict__ Vb, ushort* __restrict__ ao,
    const float* __restrict__ Wpe, const float* __restrict__ pe_scale,
    const float* __restrict__ pe_bias, float* __restrict__ v32f)
{
    __shared__ __align__(16) unsigned char smem[16384];
    const int tid = threadIdx.x;

    if (blockIdx.x < 1024) {
        // ---- attention ----
        const int w = tid >> 6, l = tid & 63;
        const int l31 = l & 31, hi = l >> 5;
        const int lid = blockIdx.x;
        const int j = lid >> 3;
        const int bh = (lid & 7) * 4 + (j >> 5);
        const int qbase = (j & 31) * 128 + w * 32;

        unsigned char (*ldsbuf)[8192] = (unsigned char(*)[8192])smem;

        const ushort* Qp = Qb + ((size_t)bh * 4096 + qbase) * 32;
        const unsigned char* Kg = (const unsigned char*)(Kt + (size_t)bh * 1024 * 32);
        const unsigned char* Vg = (const unsigned char*)(Vb + (size_t)bh * 32 * 1024);

        const bf16x8 qb0 = *(const bf16x8*)(Qp + (size_t)l31 * 32 + hi * 8);
        const bf16x8 qb1 = *(const bf16x8*)(Qp + (size_t)l31 * 32 + 16 + hi * 8);

        const int kr = tid >> 2, kc = tid & 3;
        const int vd = tid >> 3, vc = tid & 7;
        const int kwr = (kr * 64 + kc * 16) ^ ((kr & 7) << 4);
        const int vwr = vd * 128 + ((vc ^ (vd & 7)) << 4);

        f32x16 acc = {};
        float l_run = 0.f;

        uint4 kreg = *(const uint4*)(Kg + kr * 64 + kc * 16);
        uint4 vreg = *(const uint4*)(Vg + vd * 2048 + vc * 16);
        *(uint4*)(&ldsbuf[0][kwr]) = kreg;
        *(uint4*)(&ldsbuf[0][4096 + vwr]) = vreg;
        __syncthreads();

        for (int ph = 0; ph < 16; ++ph) {
            const int cur = ph & 1;
            if (ph < 15) {
                const size_t koff = (size_t)(ph + 1) * 4096;
                const int    voff = (ph + 1) * 128;
                kreg = *(const uint4*)(Kg + koff + kr * 64 + kc * 16);
                vreg = *(const uint4*)(Vg + (size_t)vd * 2048 + voff + vc * 16);
            }
            const unsigned char* Kl = &ldsbuf[cur][0];
            const unsigned char* Vl = &ldsbuf[cur][4096];

            #pragma unroll
            for (int s = 0; s < 2; ++s) {
                const int r = s * 32 + l31;
                bf16x8 ka0 = *(const bf16x8*)(Kl + ((r * 64 + hi * 16) ^ ((r & 7) << 4)));
                bf16x8 ka1 = *(const bf16x8*)(Kl + ((r * 64 + 32 + hi * 16) ^ ((r & 7) << 4)));
                bf16x8 va0 = *(const bf16x8*)(Vl + l31 * 128 + (((s * 4 + hi)     ^ (l31 & 7)) << 4));
                bf16x8 va1 = *(const bf16x8*)(Vl + l31 * 128 + (((s * 4 + 2 + hi) ^ (l31 & 7)) << 4));

                f32x16 sv = {};
                sv = __builtin_amdgcn_mfma_f32_32x32x16_bf16(ka0, qb0, sv, 0, 0, 0);
                sv = __builtin_amdgcn_mfma_f32_32x32x16_bf16(ka1, qb1, sv, 0, 0, 0);

                float p[16];
                #pragma unroll
                for (int r2 = 0; r2 < 16; ++r2) p[r2] = __builtin_amdgcn_exp2f(sv[r2]);
                l_run += (((p[0] + p[1]) + (p[2] + p[3])) + ((p[4] + p[5]) + (p[6] + p[7])))
                       + (((p[8] + p[9]) + (p[10] + p[11])) + ((p[12] + p[13]) + (p[14] + p[15])));

                int c[8];
                #pragma unroll
                for (int i = 0; i < 8; ++i)
                    asm("v_cvt_pk_bf16_f32 %0, %1, %2" : "=v"(c[i]) : "v"(p[2 * i]), "v"(p[2 * i + 1]));
                asm("v_permlane32_swap_b32 %0, %1" : "+v"(c[0]), "+v"(c[2]));
                asm("v_permlane32_swap_b32 %0, %1" : "+v"(c[1]), "+v"(c[3]));
                asm("v_permlane32_swap_b32 %0, %1" : "+v"(c[4]), "+v"(c[6]));
                asm("v_permlane32_swap_b32 %0, %1" : "+v"(c[5]), "+v"(c[7]));

                union { int i[4]; bf16x8 v; } b0u, b1u;
                b0u.i[0] = c[0]; b0u.i[1] = c[1]; b0u.i[2] = c[2]; b0u.i[3] = c[3];
                b1u.i[0] = c[4]; b1u.i[1] = c[5]; b1u.i[2] = c[6]; b1u.i[3] = c[7];

                acc = __builtin_amdgcn_mfma_f32_32x32x16_bf16(va0, b0u.v, acc, 0, 0, 0);
                acc = __builtin_amdgcn_mfma_f32_32x32x16_bf16(va1, b1u.v, acc, 0, 0, 0);
            }

            if (ph < 15) {
                const int nxt = cur ^ 1;
                *(uint4*)(&ldsbuf[nxt][kwr]) = kreg;
                *(uint4*)(&ldsbuf[nxt][4096 + vwr]) = vreg;
            }
            __syncthreads();
        }

        l_run += __shfl_xor(l_run, 32);
        float inv = 1.0f / l_run;

        ushort* aob = ao + ((size_t)(bh >> 3) * 256 + (bh & 7) * 32) * 4096 + qbase + l31;
        #pragma unroll
        for (int r = 0; r < 16; ++r) {
            const int d = (r & 3) + 8 * (r >> 2) + 4 * hi;
            aob[(size_t)d * 4096] = f2bf(acc[r] * inv);
        }
    } else {
        // ---- depthwise 7x7 (32x32 fp32 output; upsample now in proj) ----
        const int bc = blockIdx.x - 1024;
        const int b = bc >> 8, c = bc & 255;
        const ushort* vp = Vb + ((size_t)(b * 8 + (c >> 5)) * 32 + (c & 31)) * 1024;

        float* t  = (float*)smem;               // 38*38*4 = 5776 B
        float* wl = (float*)(smem + 5776);      // 196 B

        for (int i = tid; i < 38 * 38; i += 256) {
            int yy = i / 38 - 3, xx = i % 38 - 3;
            t[i] = (yy >= 0 && yy < 32 && xx >= 0 && xx < 32) ? bf2f(vp[yy * 32 + xx]) : 0.f;
        }
        if (tid < 49) wl[tid] = Wpe[(size_t)c * 49 + tid];
        __syncthreads();

        const float sc = pe_scale[c], bi = pe_bias[c];
        float* op = v32f + (size_t)bc * 1024;
        for (int i = tid; i < 1024; i += 256) {
            int y = i >> 5, x = i & 31;
            float s = 0.f;
            #pragma unroll
            for (int ky = 0; ky < 7; ++ky)
                #pragma unroll
                for (int kx = 0; kx < 7; ++kx)
                    s += t[(y + ky) * 38 + x + kx] * wl[ky * 7 + kx];
            op[i] = s * sc + bi;
        }
    }
}

// ---------------------------------------------------------------------------
// Output projection (fused transpose+add+bilinear-upsample): 512-thread
// blocks, each covering ALL o=256 for one 64-wide n-tile (= one output row
// y = blockIdx.x).  Staging computes S[n][c] = ao[c][n] + bilinear(v32f[c])
// inline (fx in {0.75,0.25} by x parity; fy uniform per block).
// 8 waves: wave w -> o-quarter (w&3)*64, n-half (w>>2)*32.
// ---------------------------------------------------------------------------
__global__ __launch_bounds__(512, 2) void proj_mfma(
    const ushort* __restrict__ Whi, const ushort* __restrict__ Wlo,
    const ushort* __restrict__ ao, const float* __restrict__ v32f,
    const float* __restrict__ scale, const float* __restrict__ bias,
    float* __restrict__ Out)
{
    __shared__ __align__(16) ushort S[64 * 256];   // 32 KB, swizzled [n][c]
    const int tid = threadIdx.x;
    const int b  = blockIdx.z;
    const int y  = blockIdx.x;             // output row; n0 = y*64
    const int n0 = y * 64;

    // ---- stage S[n][c] = ao[c][n] + vpe_bilinear(c, y, x=n-n0) ----
    {
        const int m  = tid & 15;           // x-quad: x = 4m + j, j=0..3
        const int c8 = (tid >> 4) * 8;     // 8 channels

        const int y0  = (y - 1) >> 1;
        const float fy = (y & 1) ? 0.25f : 0.75f;
        const float gy = 1.0f - fy;
        const int y0c = max(y0, 0), y1c = min(y0 + 1, 31);
        const int aIdx = max(m - 1, 0), cIdx = min(m + 1, 15);

        float sval[4][8];                  // [j][cc]
        #pragma unroll
        for (int cc = 0; cc < 8; ++cc) {
            const int ch = c8 + cc;
            const float* rowb = v32f + (size_t)(b * 256 + ch) * 1024;
            const float* rT = rowb + y0c * 32;
            const float* rB = rowb + y1c * 32;
            float2 ta = *(const float2*)(rT + 2 * aIdx);
            float2 tb = *(const float2*)(rT + 2 * m);
            float2 tc = *(const float2*)(rT + 2 * cIdx);
            float2 ba = *(const float2*)(rB + 2 * aIdx);
            float2 bb = *(const float2*)(rB + 2 * m);
            float2 bc2 = *(const float2*)(rB + 2 * cIdx);
            const float t_m1 = (m == 0)  ? tb.x : ta.y;   // pos 2m-1 (clamped)
            const float t_p2 = (m == 15) ? tb.y : tc.x;   // pos 2m+2 (clamped)
            const float b_m1 = (m == 0)  ? bb.x : ba.y;
            const float b_p2 = (m == 15) ? bb.y : bc2.x;
            // horizontal lerps: j=0 fx=.75 (x0=2m-1), j=1 fx=.25 (x0=2m),
            // j=2 fx=.75 (x0=2m), j=3 fx=.25 (x0=2m+1)
            const float ht0 = 0.25f * t_m1 + 0.75f * tb.x;
            const float ht1 = 0.75f * tb.x + 0.25f * tb.y;
            const float ht2 = 0.25f * tb.x + 0.75f * tb.y;
            const float ht3 = 0.75f * tb.y + 0.25f * t_p2;
            const float hb0 = 0.25f * b_m1 + 0.75f * bb.x;
            const float hb1 = 0.75f * bb.x + 0.25f * bb.y;
            const float hb2 = 0.25f * bb.x + 0.75f * bb.y;
            const float hb3 = 0.75f * bb.y + 0.25f * b_p2;

            const ushort* ap = ao + (size_t)(b * 256 + ch) * 4096 + n0 + m * 4;
            uint2 av = *(const uint2*)ap;
            const float a0 = bfu2f(av.x << 16);
            const float a1 = bfu2f(av.x & 0xffff0000u);
            const float a2 = bfu2f(av.y << 16);
            const float a3 = bfu2f(av.y & 0xffff0000u);

            sval[0][cc] = a0 + (gy * ht0 + fy * hb0);
            sval[1][cc] = a1 + (gy * ht1 + fy * hb1);
            sval[2][cc] = a2 + (gy * ht2 + fy * hb2);
            sval[3][cc] = a3 + (gy * ht3 + fy * hb3);
        }

        #pragma unroll
        for (int j = 0; j < 4; ++j) {
            unsigned ow[4];
            #pragma unroll
            for (int rp = 0; rp < 4; ++rp)
                asm("v_cvt_pk_bf16_f32 %0, %1, %2"
                    : "=v"(ow[rp]) : "v"(sval[j][2 * rp]), "v"(sval[j][2 * rp + 1]));
            const int n = m * 4 + j;
            const int slot = (((c8 >> 3) ^ (n & 15)) & 31);
            *(uint4*)(&S[n * 256 + (slot << 3)]) = *(const uint4*)&ow[0];
        }
    }
    __syncthreads();

    // ---- GEMM ----
    const int w = tid >> 6, l = tid & 63;
    const int l31 = l & 31, hi = l >> 5;
    const int wo = w & 3, wn = w >> 2;     // o-quarter (64), n-half (32)
    const int ob = wo * 64;

    const ushort* wh0 = Whi + (size_t)(ob + l31) * 256 + hi * 8;
    const ushort* wh1 = wh0 + (size_t)32 * 256;
    const ushort* wl0 = Wlo + (size_t)(ob + l31) * 256 + hi * 8;
    const ushort* wl1 = wl0 + (size_t)32 * 256;

    const int nloc = wn * 32 + l31;
    const ushort* Srow = &S[nloc * 256];
    const int nsw = nloc & 15;

    f32x16 acc0 = {}, acc1 = {};           // acc0: o in [ob,ob+32), acc1: +32
    #pragma unroll 4
    for (int kk = 0; kk < 256; kk += 16) {
        const int slot = (((kk >> 3) + hi) ^ nsw) & 31;
        bf16x8 av = *(const bf16x8*)(Srow + (slot << 3));
        bf16x8 h0 = *(const bf16x8*)(wh0 + kk);
        bf16x8 h1 = *(const bf16x8*)(wh1 + kk);
        bf16x8 g0 = *(const bf16x8*)(wl0 + kk);
        bf16x8 g1 = *(const bf16x8*)(wl1 + kk);
        acc0 = __builtin_amdgcn_mfma_f32_32x32x16_bf16(h0, av, acc0, 0, 0, 0);
        acc1 = __builtin_amdgcn_mfma_f32_32x32x16_bf16(h1, av, acc1, 0, 0, 0);
        acc0 = __builtin_amdgcn_mfma_f32_32x32x16_bf16(g0, av, acc0, 0, 0, 0);
        acc1 = __builtin_amdgcn_mfma_f32_32x32x16_bf16(g1, av, acc1, 0, 0, 0);
    }

    float* Ob = Out + (size_t)b * 256 * 4096 + n0 + wn * 32 + l31;
    #pragma unroll
    for (int r = 0; r < 16; ++r) {
        const int dr = (r & 3) + 8 * (r >> 2) + 4 * hi;
        const int oA = ob + dr, oB = ob + 32 + dr;
        Ob[(size_t)oA * 4096] = acc0[r] * scale[oA] + bias[oA];
        Ob[(size_t)oB * 4096] = acc1[r] * scale[oB] + bias[oB];
    }
}

// ---------------------------------------------------------------------------
extern "C" void kernel_launch(void* const* d_in, const int* in_sizes, int n_in,
                              void* d_out, int out_size, void* d_ws, size_t ws_size,
                              hipStream_t stream)
{
    const float* x        = (const float*)d_in[0];
    const float* upper    = (const float*)d_in[1];
    const float* Wq       = (const float*)d_in[2];
    const float* q_scale  = (const float*)d_in[3];
    const float* q_bias   = (const float*)d_in[4];
    const float* Wkv      = (const float*)d_in[5];
    const float* kv_scale = (const float*)d_in[6];
    const float* kv_bias  = (const float*)d_in[7];
    const float* Wpe      = (const float*)d_in[8];
    const float* pe_scale = (const float*)d_in[9];
    const float* pe_bias  = (const float*)d_in[10];
    const float* Wproj    = (const float*)d_in[11];
    const float* proj_scale = (const float*)d_in[12];
    const float* proj_bias  = (const float*)d_in[13];
    float* out = (float*)d_out;

    ushort* Qb   = (ushort*)d_ws;                           // 8.39 MB
    ushort* Kb   = Qb + (size_t)32 * 4096 * 32;             // 2.10 MB
    ushort* Vb   = Kb + (size_t)32 * 1024 * 32;             // 2.10 MB
    ushort* ao   = Vb + (size_t)32 * 1024 * 32;             // 8.39 MB bf16 [b][256][4096]
    float*  v32f = (float*)(ao + (size_t)Bq * DIM * Nq);    // 4.19 MB fp32 [b][256][32*32]
    ushort* Wqb  = (ushort*)(v32f + (size_t)Bq * DIM * Nu); // 128 KB
    ushort* Wkvb = Wqb + 256 * 256;                         // 256 KB
    ushort* Wph  = Wkvb + 512 * 256;                        // 128 KB
    ushort* Wpl  = Wph + 256 * 256;                         // 128 KB

    const float qmult = 0.17677669529663687f * 1.4426950408889634f; // qscale*log2e

    prepro<<<dim3(512), 256, 0, stream>>>(Wq, Wqb, Wkv, Wkvb, Wproj, Wph, Wpl);

    qkv_mfma<<<dim3(768), 256, 0, stream>>>(Wqb, x, q_scale, q_bias, qmult,
                                            Wkvb, upper, kv_scale, kv_bias,
                                            Qb, Kb, Vb);

    attn_dw<<<dim3(2048), 256, 0, stream>>>(Qb, Kb, Vb, ao,
                                            Wpe, pe_scale, pe_bias, v32f);

    proj_mfma<<<dim3(64, 1, 4), 512, 0, stream>>>(Wph, Wpl, ao, v32f,
                                                  proj_scale, proj_bias, out);
}